// Round 9
// baseline (274.461 us; speedup 1.0000x reference)
//
#include <hip/hip_runtime.h>
#include <hip/hip_fp16.h>
#include <math.h>
#include <string.h>

#define Nn 10000
#define Ee 320000
#define EE 330000        // E + N self loops
#define EEPS 360064      // padded(4) edge capacity + sentinel
#define INF_ 256
#define HID 128
#define OUTC 128
#define NH 4
#define F1 512
#define F2 512
#define SLOPE 0.2f
#define NB 40            // ceil(Nn/256)

static __device__ __forceinline__ float lrelu(float x) { return fmaxf(x, SLOPE * x); }

using frag_ab = __attribute__((ext_vector_type(8))) _Float16;
using frag_c  = __attribute__((ext_vector_type(4))) float;
typedef _Float16 h2v __attribute__((ext_vector_type(2)));

union U32H2 { unsigned int u; h2v h; };

#if defined(__has_builtin)
#if __has_builtin(__builtin_amdgcn_fdot2)
#define HAVE_FDOT2 1
#endif
#if __has_builtin(__builtin_amdgcn_perm)
#define HAVE_PERM 1
#endif
#endif

static __device__ __forceinline__ float fdot2f(h2v a, h2v b, float c) {
#ifdef HAVE_FDOT2
    return __builtin_amdgcn_fdot2(a, b, c, false);
#else
    return fmaf((float)a.x, (float)b.x, fmaf((float)a.y, (float)b.y, c));
#endif
}

static __device__ __forceinline__ unsigned int permsplat(unsigned int w, unsigned int sel) {
#ifdef HAVE_PERM
    return __builtin_amdgcn_perm(w, w, sel);
#else
    unsigned int lo = (sel == 0x01000100u) ? (w & 0xffffu) : (w >> 16);
    return lo | (lo << 16);
#endif
}

// ---------------- CSR build (padded-to-4 only) ----------------
__global__ void init_counts(int* counts) {
    int i = blockIdx.x * 256 + threadIdx.x;
    if (i < Nn) counts[i] = 1;  // self loop
}

__global__ void count_edges(const int* __restrict__ ei, int* counts) {
    int e = blockIdx.x * 256 + threadIdx.x;
    if (e < Ee) atomicAdd(&counts[ei[Ee + e]], 1);
}

__global__ __launch_bounds__(256) void reduce_counts(const int* __restrict__ counts,
                                                     int* __restrict__ blocksums) {
    __shared__ int sd[256];
    int t = threadIdx.x, i = blockIdx.x * 256 + t;
    int v = (i < Nn) ? ((counts[i] + 3) & ~3) : 0;
    sd[t] = v;
    __syncthreads();
    for (int off = 128; off > 0; off >>= 1) {
        if (t < off) sd[t] += sd[t + off];
        __syncthreads();
    }
    if (t == 0) blocksums[blockIdx.x] = sd[0];
}

__global__ __launch_bounds__(64) void scan_sums(int* blocksums) {
    int t = threadIdx.x;
    int orig = (t < NB) ? blocksums[t] : 0;
    int v = orig;
    for (int off = 1; off < 64; off <<= 1) {
        int u = __shfl_up(v, off);
        if (t >= off) v += u;
    }
    if (t < NB) blocksums[t] = v - orig;  // exclusive
}

__global__ __launch_bounds__(256) void scan_final(const int* __restrict__ counts,
                                                  const int* __restrict__ blocksums,
                                                  int* __restrict__ poffsets,
                                                  int* __restrict__ cursor) {
    __shared__ int sd[256];
    int t = threadIdx.x, i = blockIdx.x * 256 + t;
    int v = (i < Nn) ? ((counts[i] + 3) & ~3) : 0;
    sd[t] = v;
    __syncthreads();
    int x = v;
    for (int off = 1; off < 256; off <<= 1) {
        int u = (t >= off) ? sd[t - off] : 0;
        __syncthreads();
        x += u;
        sd[t] = x;
        __syncthreads();
    }
    int base = blocksums[blockIdx.x];
    int e = base + x - v;
    if (i < Nn) {
        poffsets[i] = e;
        cursor[i] = e;
        if (i == Nn - 1) poffsets[Nn] = e + v;
    }
}

__global__ void init_sentinel(const int* __restrict__ poffsets, int4* __restrict__ epk) {
    int tp = poffsets[Nn];
    int i = threadIdx.x;  // 8
    if (i < 8) epk[tp + i] = make_int4(0, 0, 0, 0);
}

// scatter src directly into epk[].x at padded positions
__global__ void scatter_edges(const int* __restrict__ ei, int* cursor, int4* __restrict__ epk) {
    int t = blockIdx.x * 256 + threadIdx.x;
    if (t >= EE) return;
    int src, dst;
    if (t < Ee) { src = ei[t]; dst = ei[Ee + t]; }
    else        { src = t - Ee; dst = t - Ee; }
    int pos = atomicAdd(&cursor[dst], 1);
    ((int*)epk)[pos * 4] = src;
}

// ---------------- fp32 -> fp16 conversions ----------------
__global__ void conv_f16(const float* __restrict__ in, _Float16* __restrict__ out, int n) {
    int i = blockIdx.x * 256 + threadIdx.x;
    if (i < n) out[i] = (_Float16)in[i];
}

__global__ void transpose_f16(const float* __restrict__ W, _Float16* __restrict__ WT,
                              int K, int N) {
    int n = blockIdx.x * 64 + (threadIdx.x & 63);
    int k = blockIdx.y * 4 + (threadIdx.x >> 6);
    if (n < N && k < K) WT[(size_t)n * K + k] = (_Float16)W[(size_t)k * N + n];
}

// ---------------- MFMA fp16 GEMM + fused alpha dots ----------------
#define LDK 40
__global__ __launch_bounds__(256) void mfma_gemm(const _Float16* __restrict__ A,
                                                 const _Float16* __restrict__ BT,
                                                 _Float16* __restrict__ C,
                                                 const float* __restrict__ a_src,
                                                 const float* __restrict__ a_dst,
                                                 float* __restrict__ as_out,
                                                 float* __restrict__ ad_out,
                                                 int M, int K) {
    __shared__ _Float16 As[64 * LDK];
    __shared__ _Float16 Bs[128 * LDK];
    const int tid = threadIdx.x;
    const int wave = tid >> 6, lane = tid & 63;
    const int q = lane >> 4, ml = lane & 15;
    const int bm = blockIdx.x * 64, bn = blockIdx.y * 128;
    const int head = blockIdx.y;
    const int srow = tid >> 2, scol = (tid & 3) * 8;

    frag_c acc[8];
#pragma unroll
    for (int f = 0; f < 8; f++)
#pragma unroll
        for (int r = 0; r < 4; r++) acc[f][r] = 0.f;

    for (int k0 = 0; k0 < K; k0 += 32) {
        int gm = bm + srow;
        frag_ab av;
        if (gm < M) av = *(const frag_ab*)(A + (size_t)gm * K + k0 + scol);
        else {
#pragma unroll
            for (int j = 0; j < 8; j++) av[j] = (_Float16)0.f;
        }
        *(frag_ab*)&As[srow * LDK + scol] = av;
        *(frag_ab*)&Bs[srow * LDK + scol] =
            *(const frag_ab*)(BT + (size_t)(bn + srow) * K + k0 + scol);
        *(frag_ab*)&Bs[(64 + srow) * LDK + scol] =
            *(const frag_ab*)(BT + (size_t)(bn + 64 + srow) * K + k0 + scol);
        __syncthreads();
        frag_ab a = *(frag_ab*)&As[(wave * 16 + ml) * LDK + q * 8];
#pragma unroll
        for (int f = 0; f < 8; f++) {
            frag_ab b = *(frag_ab*)&Bs[(f * 16 + ml) * LDK + q * 8];
            acc[f] = __builtin_amdgcn_mfma_f32_16x16x32_f16(a, b, acc[f], 0, 0, 0);
        }
        __syncthreads();
    }
    float asum[4] = {}, dsum[4] = {};
#pragma unroll
    for (int f = 0; f < 8; f++) {
        int cl = f * 16 + ml;
        int col = bn + cl;
        float sa = a_src[head * 128 + cl];
        float da = a_dst[head * 128 + cl];
#pragma unroll
        for (int r = 0; r < 4; r++) {
            int row = bm + wave * 16 + q * 4 + r;
            if (row < M) C[(size_t)row * (NH * 128) + col] = (_Float16)acc[f][r];
            asum[r] += acc[f][r] * sa;
            dsum[r] += acc[f][r] * da;
        }
    }
#pragma unroll
    for (int r = 0; r < 4; r++) {
#pragma unroll
        for (int off = 1; off < 16; off <<= 1) {
            asum[r] += __shfl_xor(asum[r], off);
            dsum[r] += __shfl_xor(dsum[r], off);
        }
    }
    if (ml == 0) {
#pragma unroll
        for (int r = 0; r < 4; r++) {
            int row = bm + wave * 16 + q * 4 + r;
            if (row < M) {
                as_out[row * NH + head] = asum[r];
                ad_out[row * NH + head] = dsum[r];
            }
        }
    }
}

// ---------------- pass A: quarter-wave per node; writes packed int4 epk ----------------
__global__ __launch_bounds__(256) void passA(const int* __restrict__ poffsets,
                                             const int* __restrict__ ends,
                                             const float* __restrict__ as,
                                             const float* __restrict__ ad,
                                             int4* __restrict__ epk,
                                             float* __restrict__ invd) {
    int n = blockIdx.x * 16 + (threadIdx.x >> 4);
    int l = threadIdx.x & 15;
    int pstart = poffsets[n], pend = poffsets[n + 1];
    int dend = ends[n];  // pstart + deg
    const int* epx = (const int*)epk;
    float4 adv = *(const float4*)&ad[n * NH];
    float m0 = -1e30f, m1 = -1e30f, m2 = -1e30f, m3 = -1e30f;
    for (int pos = pstart + l; pos < dend; pos += 16) {
        int src = epx[pos * 4];
        float4 asv = *(const float4*)&as[src * NH];
        m0 = fmaxf(m0, lrelu(asv.x + adv.x));
        m1 = fmaxf(m1, lrelu(asv.y + adv.y));
        m2 = fmaxf(m2, lrelu(asv.z + adv.z));
        m3 = fmaxf(m3, lrelu(asv.w + adv.w));
    }
#pragma unroll
    for (int off = 8; off > 0; off >>= 1) {
        m0 = fmaxf(m0, __shfl_xor(m0, off));
        m1 = fmaxf(m1, __shfl_xor(m1, off));
        m2 = fmaxf(m2, __shfl_xor(m2, off));
        m3 = fmaxf(m3, __shfl_xor(m3, off));
    }
    float s0 = 0.f, s1 = 0.f, s2 = 0.f, s3 = 0.f;
    for (int pos = pstart + l; pos < pend; pos += 16) {
        int src = 0;
        float e0 = 0.f, e1 = 0.f, e2 = 0.f, e3 = 0.f;
        if (pos < dend) {
            src = epx[pos * 4];
            float4 asv = *(const float4*)&as[src * NH];
            e0 = __expf(lrelu(asv.x + adv.x) - m0);
            e1 = __expf(lrelu(asv.y + adv.y) - m1);
            e2 = __expf(lrelu(asv.z + adv.z) - m2);
            e3 = __expf(lrelu(asv.w + adv.w) - m3);
        }
        __half2 p01 = __floats2half2_rn(e0, e1);
        __half2 p23 = __floats2half2_rn(e2, e3);
        int w01, w23;
        memcpy(&w01, &p01, 4);
        memcpy(&w23, &p23, 4);
        epk[pos] = make_int4(src, w01, w23, 0);
        s0 += e0; s1 += e1; s2 += e2; s3 += e3;
    }
#pragma unroll
    for (int off = 8; off > 0; off >>= 1) {
        s0 += __shfl_xor(s0, off);
        s1 += __shfl_xor(s1, off);
        s2 += __shfl_xor(s2, off);
        s3 += __shfl_xor(s3, off);
    }
    if (l == 0) {
        *(float4*)&invd[n * NH] = make_float4(1.f / (s0 + 1e-16f), 1.f / (s1 + 1e-16f),
                                              1.f / (s2 + 1e-16f), 1.f / (s3 + 1e-16f));
    }
}

// ---------------- pass B: full-row wave per node, fdot2, no shuffles ----------------
// wave = 1 node; lane owns 8 ch (c = lane*8); head = lane>>4; 2 edges/iter.
__global__ __launch_bounds__(256) void passB1r(const int* __restrict__ poffsets,
                                               const int4* __restrict__ epk,
                                               const float* __restrict__ invd,
                                               const _Float16* __restrict__ hh,
                                               const float* __restrict__ b1,
                                               _Float16* __restrict__ agg) {
    int n = blockIdx.x * 4 + (threadIdx.x >> 6);
    int lane = threadIdx.x & 63;
    int head = lane >> 4;
    int c = lane << 3;
    unsigned int sel = (head & 1) ? 0x03020302u : 0x01000100u;
    int pstart = poffsets[n], pend = poffsets[n + 1];
    float4 bv0 = *(const float4*)&b1[c];
    float4 bv1 = *(const float4*)&b1[c + 4];
    float acc0 = 0.f, acc1 = 0.f, acc2 = 0.f, acc3 = 0.f;
    int idx = pstart;
    int4 p0 = epk[idx];
    int4 p1 = epk[idx + 1];
    while (idx < pend) {
        int4 q0 = epk[idx + 2];
        int4 q1 = epk[idx + 3];
        {
            unsigned int ww = (head < 2) ? (unsigned int)p0.y : (unsigned int)p0.z;
            U32H2 u; u.u = permsplat(ww, sel);
            int4 rv = *(const int4*)(hh + (size_t)p0.x * F1 + c);
            U32H2 h0, h1c, h2c, h3;
            h0.u = rv.x; h1c.u = rv.y; h2c.u = rv.z; h3.u = rv.w;
            acc0 = fdot2f(h0.h, u.h, acc0);
            acc1 = fdot2f(h1c.h, u.h, acc1);
            acc2 = fdot2f(h2c.h, u.h, acc2);
            acc3 = fdot2f(h3.h, u.h, acc3);
        }
        {
            unsigned int ww = (head < 2) ? (unsigned int)p1.y : (unsigned int)p1.z;
            U32H2 u; u.u = permsplat(ww, sel);
            int4 rv = *(const int4*)(hh + (size_t)p1.x * F1 + c);
            U32H2 h0, h1c, h2c, h3;
            h0.u = rv.x; h1c.u = rv.y; h2c.u = rv.z; h3.u = rv.w;
            acc0 = fdot2f(h0.h, u.h, acc0);
            acc1 = fdot2f(h1c.h, u.h, acc1);
            acc2 = fdot2f(h2c.h, u.h, acc2);
            acc3 = fdot2f(h3.h, u.h, acc3);
        }
        idx += 2; p0 = q0; p1 = q1;
    }
    float inv = invd[n * NH + head];
    _Float16 oh[8];
    float a[8] = {acc0, acc0, acc1, acc1, acc2, acc2, acc3, acc3};
    // unpack: acc0 holds ch c,c+1 via fdot2 pairs — recompute properly below
    // (fdot2 sums the PAIR, so acc0 = sum over ch c and c+1 combined — wrong!)
    (void)a; (void)oh; (void)bv0; (void)bv1; (void)inv;
}

// NOTE: fdot2 sums channel pairs — need per-channel outputs. Use fma_mix-style
// per-channel accumulation instead (w splat as float).
__global__ __launch_bounds__(256) void passB1f(const int* __restrict__ poffsets,
                                               const int4* __restrict__ epk,
                                               const float* __restrict__ invd,
                                               const _Float16* __restrict__ hh,
                                               const float* __restrict__ b1,
                                               _Float16* __restrict__ agg) {
    int n = blockIdx.x * 4 + (threadIdx.x >> 6);
    int lane = threadIdx.x & 63;
    int head = lane >> 4;
    int c = lane << 3;
    unsigned int sel = (head & 1) ? 0x03020302u : 0x01000100u;
    int pstart = poffsets[n], pend = poffsets[n + 1];
    float acc[8] = {};
    int idx = pstart;
    int4 p0 = epk[idx];
    int4 p1 = epk[idx + 1];
    while (idx < pend) {
        int4 q0 = epk[idx + 2];
        int4 q1 = epk[idx + 3];
        {
            unsigned int ww = (head < 2) ? (unsigned int)p0.y : (unsigned int)p0.z;
            U32H2 u; u.u = permsplat(ww, sel);
            h2v wh = u.h;
            frag_ab rv = *(const frag_ab*)(hh + (size_t)p0.x * F1 + c);
#pragma unroll
            for (int j = 0; j < 4; j++) {
                h2v hp = {rv[2 * j], rv[2 * j + 1]};
                acc[2 * j]     = fmaf((float)hp.x, (float)wh.x, acc[2 * j]);
                acc[2 * j + 1] = fmaf((float)hp.y, (float)wh.y, acc[2 * j + 1]);
            }
        }
        {
            unsigned int ww = (head < 2) ? (unsigned int)p1.y : (unsigned int)p1.z;
            U32H2 u; u.u = permsplat(ww, sel);
            h2v wh = u.h;
            frag_ab rv = *(const frag_ab*)(hh + (size_t)p1.x * F1 + c);
#pragma unroll
            for (int j = 0; j < 4; j++) {
                h2v hp = {rv[2 * j], rv[2 * j + 1]};
                acc[2 * j]     = fmaf((float)hp.x, (float)wh.x, acc[2 * j]);
                acc[2 * j + 1] = fmaf((float)hp.y, (float)wh.y, acc[2 * j + 1]);
            }
        }
        idx += 2; p0 = q0; p1 = q1;
    }
    float inv = invd[n * NH + head];
    float4 bv0 = *(const float4*)&b1[c];
    float4 bv1 = *(const float4*)&b1[c + 4];
    float bb[8] = {bv0.x, bv0.y, bv0.z, bv0.w, bv1.x, bv1.y, bv1.z, bv1.w};
    _Float16 oh[8];
#pragma unroll
    for (int j = 0; j < 8; j++)
        oh[j] = (_Float16)fmaxf(acc[j] * inv + bb[j], 0.f);
    *(float4*)&agg[(size_t)n * F1 + c] = *(float4*)oh;
}

__global__ __launch_bounds__(256) void passB2f(const int* __restrict__ poffsets,
                                               const int4* __restrict__ epk,
                                               const float* __restrict__ invd,
                                               const _Float16* __restrict__ hh,
                                               float* __restrict__ tmp) {
    int n = blockIdx.x * 4 + (threadIdx.x >> 6);
    int lane = threadIdx.x & 63;
    int head = lane >> 4;
    int c = lane << 3;
    unsigned int sel = (head & 1) ? 0x03020302u : 0x01000100u;
    int pstart = poffsets[n], pend = poffsets[n + 1];
    float acc[8] = {};
    int idx = pstart;
    int4 p0 = epk[idx];
    int4 p1 = epk[idx + 1];
    while (idx < pend) {
        int4 q0 = epk[idx + 2];
        int4 q1 = epk[idx + 3];
        {
            unsigned int ww = (head < 2) ? (unsigned int)p0.y : (unsigned int)p0.z;
            U32H2 u; u.u = permsplat(ww, sel);
            h2v wh = u.h;
            frag_ab rv = *(const frag_ab*)(hh + (size_t)p0.x * F2 + c);
#pragma unroll
            for (int j = 0; j < 4; j++) {
                h2v hp = {rv[2 * j], rv[2 * j + 1]};
                acc[2 * j]     = fmaf((float)hp.x, (float)wh.x, acc[2 * j]);
                acc[2 * j + 1] = fmaf((float)hp.y, (float)wh.y, acc[2 * j + 1]);
            }
        }
        {
            unsigned int ww = (head < 2) ? (unsigned int)p1.y : (unsigned int)p1.z;
            U32H2 u; u.u = permsplat(ww, sel);
            h2v wh = u.h;
            frag_ab rv = *(const frag_ab*)(hh + (size_t)p1.x * F2 + c);
#pragma unroll
            for (int j = 0; j < 4; j++) {
                h2v hp = {rv[2 * j], rv[2 * j + 1]};
                acc[2 * j]     = fmaf((float)hp.x, (float)wh.x, acc[2 * j]);
                acc[2 * j + 1] = fmaf((float)hp.y, (float)wh.y, acc[2 * j + 1]);
            }
        }
        idx += 2; p0 = q0; p1 = q1;
    }
    float q = 0.25f * invd[n * NH + head];
    float* tp = tmp + (size_t)n * F2 + c;
    float4 o0 = make_float4(acc[0] * q, acc[1] * q, acc[2] * q, acc[3] * q);
    float4 o1 = make_float4(acc[4] * q, acc[5] * q, acc[6] * q, acc[7] * q);
    *(float4*)tp = o0;
    *(float4*)(tp + 4) = o1;
}

// ---------------- reduce 4 heads + bias -> d_out (tmp layout [n][head][128]) ----------------
__global__ void reduce4(const float* __restrict__ tmp, const float* __restrict__ b2,
                        float* __restrict__ out) {
    int i = blockIdx.x * 256 + threadIdx.x;
    if (i >= Nn * OUTC) return;
    int n = i >> 7, oc = i & 127;
    const float* tp = tmp + (size_t)n * 512 + oc;
    out[i] = tp[0] + tp[128] + tp[256] + tp[384] + b2[oc];
}

extern "C" void kernel_launch(void* const* d_in, const int* in_sizes, int n_in,
                              void* d_out, int out_size, void* d_ws, size_t ws_size,
                              hipStream_t stream) {
    const float* x      = (const float*)d_in[0];
    const int*   ei     = (const int*)d_in[1];
    const float* W1     = (const float*)d_in[2];
    const float* a_src1 = (const float*)d_in[3];
    const float* a_dst1 = (const float*)d_in[4];
    const float* b1     = (const float*)d_in[5];
    const float* W2     = (const float*)d_in[6];
    const float* a_src2 = (const float*)d_in[7];
    const float* a_dst2 = (const float*)d_in[8];
    const float* b2     = (const float*)d_in[9];
    float* out = (float*)d_out;

    const size_t NF = (size_t)Nn * F1;
    float* f = (float*)d_ws;
    float* tmp   = f;                    // NF floats [n][head][128]
    float* as1   = tmp + NF;
    float* ad1   = as1 + Nn * NH;
    float* as2   = ad1 + Nn * NH;
    float* ad2   = as2 + Nn * NH;
    float* invd1 = ad2 + Nn * NH;
    float* invd2 = invd1 + Nn * NH;
    int4* epk    = (int4*)(invd2 + Nn * NH);        // EEPS int4
    _Float16* hh   = (_Float16*)(epk + (size_t)EEPS);
    _Float16* aggh = hh + NF;
    _Float16* xh   = aggh + NF;
    _Float16* w1t  = xh + (size_t)Nn * INF_;
    _Float16* w2t  = w1t + (size_t)F1 * INF_;
    int* counts    = (int*)(w2t + (size_t)F2 * F1);
    int* poffsets  = counts + Nn;
    int* cursor    = poffsets + Nn + 1;
    int* blocksums = cursor + Nn;

    // CSR build (padded-to-4; src written straight into epk.x)
    init_counts<<<(Nn + 255) / 256, 256, 0, stream>>>(counts);
    count_edges<<<(Ee + 255) / 256, 256, 0, stream>>>(ei, counts);
    reduce_counts<<<NB, 256, 0, stream>>>(counts, blocksums);
    scan_sums<<<1, 64, 0, stream>>>(blocksums);
    scan_final<<<NB, 256, 0, stream>>>(counts, blocksums, poffsets, cursor);
    scatter_edges<<<(EE + 255) / 256, 256, 0, stream>>>(ei, cursor, epk);
    init_sentinel<<<1, 64, 0, stream>>>(poffsets, epk);

    // fp16 conversions
    conv_f16<<<(Nn * INF_ + 255) / 256, 256, 0, stream>>>(x, xh, Nn * INF_);
    transpose_f16<<<dim3(F1 / 64, INF_ / 4), 256, 0, stream>>>(W1, w1t, INF_, F1);
    transpose_f16<<<dim3(F2 / 64, F1 / 4), 256, 0, stream>>>(W2, w2t, F1, F2);

    // Layer 1
    mfma_gemm<<<dim3((Nn + 63) / 64, F1 / 128), 256, 0, stream>>>(
        xh, w1t, hh, a_src1, a_dst1, as1, ad1, Nn, INF_);
    passA<<<Nn / 16, 256, 0, stream>>>(poffsets, cursor, as1, ad1, epk, invd1);
    passB1f<<<Nn / 4, 256, 0, stream>>>(poffsets, epk, invd1, hh, b1, aggh);

    // Layer 2
    mfma_gemm<<<dim3((Nn + 63) / 64, F2 / 128), 256, 0, stream>>>(
        aggh, w2t, hh, a_src2, a_dst2, as2, ad2, Nn, F1);
    passA<<<Nn / 16, 256, 0, stream>>>(poffsets, cursor, as2, ad2, epk, invd2);
    passB2f<<<Nn / 4, 256, 0, stream>>>(poffsets, epk, invd2, hh, tmp);
    reduce4<<<(Nn * OUTC + 255) / 256, 256, 0, stream>>>(tmp, b2, out);
}

// Round 10
// 262.550 us; speedup vs baseline: 1.0454x; 1.0454x over previous
//
#include <hip/hip_runtime.h>
#include <hip/hip_fp16.h>
#include <math.h>
#include <string.h>

#define Nn 10000
#define Ee 320000
#define EE 330000        // E + N self loops
#define EEPS 360064      // padded(4) edge capacity + sentinel
#define INF_ 256
#define HID 128
#define OUTC 128
#define NH 4
#define F1 512
#define F2 512
#define SLOPE 0.2f
#define NB 40            // ceil(Nn/256)

static __device__ __forceinline__ float lrelu(float x) { return fmaxf(x, SLOPE * x); }

using frag_ab = __attribute__((ext_vector_type(8))) _Float16;
using frag_c  = __attribute__((ext_vector_type(4))) float;
typedef _Float16 h2v __attribute__((ext_vector_type(2)));

union U32H2 { unsigned int u; h2v h; };

// ---------------- CSR build (padded-to-4, src scattered into epk.x) ----------------
__global__ void init_counts(int* counts) {
    int i = blockIdx.x * 256 + threadIdx.x;
    if (i < Nn) counts[i] = 1;  // self loop
}

__global__ void count_edges(const int* __restrict__ ei, int* counts) {
    int e = blockIdx.x * 256 + threadIdx.x;
    if (e < Ee) atomicAdd(&counts[ei[Ee + e]], 1);
}

__global__ __launch_bounds__(256) void reduce_counts(const int* __restrict__ counts,
                                                     int* __restrict__ blocksums) {
    __shared__ int sd[256];
    int t = threadIdx.x, i = blockIdx.x * 256 + t;
    int v = (i < Nn) ? ((counts[i] + 3) & ~3) : 0;
    sd[t] = v;
    __syncthreads();
    for (int off = 128; off > 0; off >>= 1) {
        if (t < off) sd[t] += sd[t + off];
        __syncthreads();
    }
    if (t == 0) blocksums[blockIdx.x] = sd[0];
}

__global__ __launch_bounds__(64) void scan_sums(int* blocksums) {
    int t = threadIdx.x;
    int orig = (t < NB) ? blocksums[t] : 0;
    int v = orig;
    for (int off = 1; off < 64; off <<= 1) {
        int u = __shfl_up(v, off);
        if (t >= off) v += u;
    }
    if (t < NB) blocksums[t] = v - orig;  // exclusive
}

__global__ __launch_bounds__(256) void scan_final(const int* __restrict__ counts,
                                                  const int* __restrict__ blocksums,
                                                  int* __restrict__ poffsets,
                                                  int* __restrict__ cursor) {
    __shared__ int sd[256];
    int t = threadIdx.x, i = blockIdx.x * 256 + t;
    int v = (i < Nn) ? ((counts[i] + 3) & ~3) : 0;
    sd[t] = v;
    __syncthreads();
    int x = v;
    for (int off = 1; off < 256; off <<= 1) {
        int u = (t >= off) ? sd[t - off] : 0;
        __syncthreads();
        x += u;
        sd[t] = x;
        __syncthreads();
    }
    int base = blocksums[blockIdx.x];
    int e = base + x - v;
    if (i < Nn) {
        poffsets[i] = e;
        cursor[i] = e;
        if (i == Nn - 1) poffsets[Nn] = e + v;
    }
}

__global__ void init_sentinel(const int* __restrict__ poffsets, int4* __restrict__ epk) {
    int tp = poffsets[Nn];
    int i = threadIdx.x;  // 64
    if (i < 8) epk[tp + i] = make_int4(0, 0, 0, 0);
}

__global__ void scatter_edges(const int* __restrict__ ei, int* cursor, int4* __restrict__ epk) {
    int t = blockIdx.x * 256 + threadIdx.x;
    if (t >= EE) return;
    int src, dst;
    if (t < Ee) { src = ei[t]; dst = ei[Ee + t]; }
    else        { src = t - Ee; dst = t - Ee; }
    int pos = atomicAdd(&cursor[dst], 1);
    ((int*)epk)[pos * 4] = src;
}

// ---------------- fp32 -> fp16 conversions ----------------
__global__ void conv_f16(const float* __restrict__ in, _Float16* __restrict__ out, int n) {
    int i = blockIdx.x * 256 + threadIdx.x;
    if (i < n) out[i] = (_Float16)in[i];
}

__global__ void transpose_f16(const float* __restrict__ W, _Float16* __restrict__ WT,
                              int K, int N) {
    int n = blockIdx.x * 64 + (threadIdx.x & 63);
    int k = blockIdx.y * 4 + (threadIdx.x >> 6);
    if (n < N && k < K) WT[(size_t)n * K + k] = (_Float16)W[(size_t)k * N + n];
}

// ---------------- MFMA fp16 GEMM + fused alpha dots ----------------
#define LDK 40
__global__ __launch_bounds__(256) void mfma_gemm(const _Float16* __restrict__ A,
                                                 const _Float16* __restrict__ BT,
                                                 _Float16* __restrict__ C,
                                                 const float* __restrict__ a_src,
                                                 const float* __restrict__ a_dst,
                                                 float* __restrict__ as_out,
                                                 float* __restrict__ ad_out,
                                                 int M, int K) {
    __shared__ _Float16 As[64 * LDK];
    __shared__ _Float16 Bs[128 * LDK];
    const int tid = threadIdx.x;
    const int wave = tid >> 6, lane = tid & 63;
    const int q = lane >> 4, ml = lane & 15;
    const int bm = blockIdx.x * 64, bn = blockIdx.y * 128;
    const int head = blockIdx.y;
    const int srow = tid >> 2, scol = (tid & 3) * 8;

    frag_c acc[8];
#pragma unroll
    for (int f = 0; f < 8; f++)
#pragma unroll
        for (int r = 0; r < 4; r++) acc[f][r] = 0.f;

    for (int k0 = 0; k0 < K; k0 += 32) {
        int gm = bm + srow;
        frag_ab av;
        if (gm < M) av = *(const frag_ab*)(A + (size_t)gm * K + k0 + scol);
        else {
#pragma unroll
            for (int j = 0; j < 8; j++) av[j] = (_Float16)0.f;
        }
        *(frag_ab*)&As[srow * LDK + scol] = av;
        *(frag_ab*)&Bs[srow * LDK + scol] =
            *(const frag_ab*)(BT + (size_t)(bn + srow) * K + k0 + scol);
        *(frag_ab*)&Bs[(64 + srow) * LDK + scol] =
            *(const frag_ab*)(BT + (size_t)(bn + 64 + srow) * K + k0 + scol);
        __syncthreads();
        frag_ab a = *(frag_ab*)&As[(wave * 16 + ml) * LDK + q * 8];
#pragma unroll
        for (int f = 0; f < 8; f++) {
            frag_ab b = *(frag_ab*)&Bs[(f * 16 + ml) * LDK + q * 8];
            acc[f] = __builtin_amdgcn_mfma_f32_16x16x32_f16(a, b, acc[f], 0, 0, 0);
        }
        __syncthreads();
    }
    float asum[4] = {}, dsum[4] = {};
#pragma unroll
    for (int f = 0; f < 8; f++) {
        int cl = f * 16 + ml;
        int col = bn + cl;
        float sa = a_src[head * 128 + cl];
        float da = a_dst[head * 128 + cl];
#pragma unroll
        for (int r = 0; r < 4; r++) {
            int row = bm + wave * 16 + q * 4 + r;
            if (row < M) C[(size_t)row * (NH * 128) + col] = (_Float16)acc[f][r];
            asum[r] += acc[f][r] * sa;
            dsum[r] += acc[f][r] * da;
        }
    }
#pragma unroll
    for (int r = 0; r < 4; r++) {
#pragma unroll
        for (int off = 1; off < 16; off <<= 1) {
            asum[r] += __shfl_xor(asum[r], off);
            dsum[r] += __shfl_xor(dsum[r], off);
        }
    }
    if (ml == 0) {
#pragma unroll
        for (int r = 0; r < 4; r++) {
            int row = bm + wave * 16 + q * 4 + r;
            if (row < M) {
                as_out[row * NH + head] = asum[r];
                ad_out[row * NH + head] = dsum[r];
            }
        }
    }
}

// ---------------- pass A: quarter-wave per node; writes packed int4 epk ----------------
__global__ __launch_bounds__(256) void passA(const int* __restrict__ poffsets,
                                             const int* __restrict__ ends,
                                             const float* __restrict__ as,
                                             const float* __restrict__ ad,
                                             int4* __restrict__ epk,
                                             float* __restrict__ invd) {
    int n = blockIdx.x * 16 + (threadIdx.x >> 4);
    int l = threadIdx.x & 15;
    int pstart = poffsets[n], pend = poffsets[n + 1];
    int dend = ends[n];  // pstart + deg
    const int* epx = (const int*)epk;
    float4 adv = *(const float4*)&ad[n * NH];
    float m0 = -1e30f, m1 = -1e30f, m2 = -1e30f, m3 = -1e30f;
    for (int pos = pstart + l; pos < dend; pos += 16) {
        int src = epx[pos * 4];
        float4 asv = *(const float4*)&as[src * NH];
        m0 = fmaxf(m0, lrelu(asv.x + adv.x));
        m1 = fmaxf(m1, lrelu(asv.y + adv.y));
        m2 = fmaxf(m2, lrelu(asv.z + adv.z));
        m3 = fmaxf(m3, lrelu(asv.w + adv.w));
    }
#pragma unroll
    for (int off = 8; off > 0; off >>= 1) {
        m0 = fmaxf(m0, __shfl_xor(m0, off));
        m1 = fmaxf(m1, __shfl_xor(m1, off));
        m2 = fmaxf(m2, __shfl_xor(m2, off));
        m3 = fmaxf(m3, __shfl_xor(m3, off));
    }
    float s0 = 0.f, s1 = 0.f, s2 = 0.f, s3 = 0.f;
    for (int pos = pstart + l; pos < pend; pos += 16) {
        int src = 0;
        float e0 = 0.f, e1 = 0.f, e2 = 0.f, e3 = 0.f;
        if (pos < dend) {
            src = epx[pos * 4];
            float4 asv = *(const float4*)&as[src * NH];
            e0 = __expf(lrelu(asv.x + adv.x) - m0);
            e1 = __expf(lrelu(asv.y + adv.y) - m1);
            e2 = __expf(lrelu(asv.z + adv.z) - m2);
            e3 = __expf(lrelu(asv.w + adv.w) - m3);
        }
        __half2 p01 = __floats2half2_rn(e0, e1);
        __half2 p23 = __floats2half2_rn(e2, e3);
        int w01, w23;
        memcpy(&w01, &p01, 4);
        memcpy(&w23, &p23, 4);
        epk[pos] = make_int4(src, w01, w23, 0);
        s0 += e0; s1 += e1; s2 += e2; s3 += e3;
    }
#pragma unroll
    for (int off = 8; off > 0; off >>= 1) {
        s0 += __shfl_xor(s0, off);
        s1 += __shfl_xor(s1, off);
        s2 += __shfl_xor(s2, off);
        s3 += __shfl_xor(s3, off);
    }
    if (l == 0) {
        *(float4*)&invd[n * NH] = make_float4(1.f / (s0 + 1e-16f), 1.f / (s1 + 1e-16f),
                                              1.f / (s2 + 1e-16f), 1.f / (s3 + 1e-16f));
    }
}

// ---------------- pass B: head-sliced (blockIdx&3 -> XCD) + shuffle-free ----------------
// Block = 16 nodes x 1 head. Quarter-wave (16 lanes) = one node: lane sl owns 8 ch
// of the head's 128; edges serial, 2-unrolled, guard-free (pad-4 + sentinel).
// Per-XCD slice working set = 10000*128*2B = 2.56 MB -> L2-resident.
__global__ __launch_bounds__(256) void passB1s(const int* __restrict__ poffsets,
                                               const int4* __restrict__ epk,
                                               const float* __restrict__ invd,
                                               const _Float16* __restrict__ hh,
                                               const float* __restrict__ b1,
                                               _Float16* __restrict__ agg) {
    int head = blockIdx.x & 3;
    int nb = (blockIdx.x >> 2) * 16;
    int wave = threadIdx.x >> 6, lane = threadIdx.x & 63;
    int sub = lane >> 4, sl = lane & 15;
    int n = nb + wave * 4 + sub;
    int c = head * 128 + (sl << 3);
    int pstart = poffsets[n], pend = poffsets[n + 1];
    bool hi = (head & 1);
    float acc[8] = {};
    int idx = pstart;
    int4 p0 = epk[idx];
    int4 p1 = epk[idx + 1];
    while (idx < pend) {
        int4 q0 = epk[idx + 2];
        int4 q1 = epk[idx + 3];
        U32H2 u0, u1;
        u0.u = (head < 2) ? (unsigned int)p0.y : (unsigned int)p0.z;
        u1.u = (head < 2) ? (unsigned int)p1.y : (unsigned int)p1.z;
        float w0 = hi ? (float)u0.h.y : (float)u0.h.x;
        float w1 = hi ? (float)u1.h.y : (float)u1.h.x;
        frag_ab r0 = *(const frag_ab*)(hh + (size_t)p0.x * F1 + c);
        frag_ab r1 = *(const frag_ab*)(hh + (size_t)p1.x * F1 + c);
#pragma unroll
        for (int j = 0; j < 8; j++) {
            acc[j] = fmaf((float)r0[j], w0, acc[j]);
            acc[j] = fmaf((float)r1[j], w1, acc[j]);
        }
        idx += 2; p0 = q0; p1 = q1;
    }
    float inv = invd[n * NH + head];
    _Float16 oh[8];
#pragma unroll
    for (int j = 0; j < 8; j++)
        oh[j] = (_Float16)fmaxf(acc[j] * inv + b1[c + j], 0.f);
    *(float4*)&agg[(size_t)n * F1 + c] = *(float4*)oh;
}

__global__ __launch_bounds__(256) void passB2s(const int* __restrict__ poffsets,
                                               const int4* __restrict__ epk,
                                               const float* __restrict__ invd,
                                               const _Float16* __restrict__ hh,
                                               float* __restrict__ tmp) {
    int head = blockIdx.x & 3;
    int nb = (blockIdx.x >> 2) * 16;
    int wave = threadIdx.x >> 6, lane = threadIdx.x & 63;
    int sub = lane >> 4, sl = lane & 15;
    int n = nb + wave * 4 + sub;
    int c = head * 128 + (sl << 3);
    int pstart = poffsets[n], pend = poffsets[n + 1];
    bool hi = (head & 1);
    float acc[8] = {};
    int idx = pstart;
    int4 p0 = epk[idx];
    int4 p1 = epk[idx + 1];
    while (idx < pend) {
        int4 q0 = epk[idx + 2];
        int4 q1 = epk[idx + 3];
        U32H2 u0, u1;
        u0.u = (head < 2) ? (unsigned int)p0.y : (unsigned int)p0.z;
        u1.u = (head < 2) ? (unsigned int)p1.y : (unsigned int)p1.z;
        float w0 = hi ? (float)u0.h.y : (float)u0.h.x;
        float w1 = hi ? (float)u1.h.y : (float)u1.h.x;
        frag_ab r0 = *(const frag_ab*)(hh + (size_t)p0.x * F2 + c);
        frag_ab r1 = *(const frag_ab*)(hh + (size_t)p1.x * F2 + c);
#pragma unroll
        for (int j = 0; j < 8; j++) {
            acc[j] = fmaf((float)r0[j], w0, acc[j]);
            acc[j] = fmaf((float)r1[j], w1, acc[j]);
        }
        idx += 2; p0 = q0; p1 = q1;
    }
    float qq = 0.25f * invd[n * NH + head];
    float* tp = tmp + (size_t)n * F2 + c;   // layout [n][head*128+ch]
    float4 o0 = make_float4(acc[0] * qq, acc[1] * qq, acc[2] * qq, acc[3] * qq);
    float4 o1 = make_float4(acc[4] * qq, acc[5] * qq, acc[6] * qq, acc[7] * qq);
    *(float4*)tp = o0;
    *(float4*)(tp + 4) = o1;
}

// ---------------- reduce 4 heads + bias -> d_out (tmp layout [n][head][128]) ----------------
__global__ void reduce4(const float* __restrict__ tmp, const float* __restrict__ b2,
                        float* __restrict__ out) {
    int i = blockIdx.x * 256 + threadIdx.x;
    if (i >= Nn * OUTC) return;
    int n = i >> 7, oc = i & 127;
    const float* tp = tmp + (size_t)n * 512 + oc;
    out[i] = tp[0] + tp[128] + tp[256] + tp[384] + b2[oc];
}

extern "C" void kernel_launch(void* const* d_in, const int* in_sizes, int n_in,
                              void* d_out, int out_size, void* d_ws, size_t ws_size,
                              hipStream_t stream) {
    const float* x      = (const float*)d_in[0];
    const int*   ei     = (const int*)d_in[1];
    const float* W1     = (const float*)d_in[2];
    const float* a_src1 = (const float*)d_in[3];
    const float* a_dst1 = (const float*)d_in[4];
    const float* b1     = (const float*)d_in[5];
    const float* W2     = (const float*)d_in[6];
    const float* a_src2 = (const float*)d_in[7];
    const float* a_dst2 = (const float*)d_in[8];
    const float* b2     = (const float*)d_in[9];
    float* out = (float*)d_out;

    const size_t NF = (size_t)Nn * F1;
    float* f = (float*)d_ws;
    float* tmp   = f;                    // NF floats [n][head][128]
    float* as1   = tmp + NF;
    float* ad1   = as1 + Nn * NH;
    float* as2   = ad1 + Nn * NH;
    float* ad2   = as2 + Nn * NH;
    float* invd1 = ad2 + Nn * NH;
    float* invd2 = invd1 + Nn * NH;
    int4* epk    = (int4*)(invd2 + Nn * NH);        // EEPS int4
    _Float16* hh   = (_Float16*)(epk + (size_t)EEPS);
    _Float16* aggh = hh + NF;
    _Float16* xh   = aggh + NF;
    _Float16* w1t  = xh + (size_t)Nn * INF_;
    _Float16* w2t  = w1t + (size_t)F1 * INF_;
    int* counts    = (int*)(w2t + (size_t)F2 * F1);
    int* poffsets  = counts + Nn;
    int* cursor    = poffsets + Nn + 1;
    int* blocksums = cursor + Nn;

    // CSR build (padded-to-4; src written straight into epk.x)
    init_counts<<<(Nn + 255) / 256, 256, 0, stream>>>(counts);
    count_edges<<<(Ee + 255) / 256, 256, 0, stream>>>(ei, counts);
    reduce_counts<<<NB, 256, 0, stream>>>(counts, blocksums);
    scan_sums<<<1, 64, 0, stream>>>(blocksums);
    scan_final<<<NB, 256, 0, stream>>>(counts, blocksums, poffsets, cursor);
    scatter_edges<<<(EE + 255) / 256, 256, 0, stream>>>(ei, cursor, epk);
    init_sentinel<<<1, 64, 0, stream>>>(poffsets, epk);

    // fp16 conversions
    conv_f16<<<(Nn * INF_ + 255) / 256, 256, 0, stream>>>(x, xh, Nn * INF_);
    transpose_f16<<<dim3(F1 / 64, INF_ / 4), 256, 0, stream>>>(W1, w1t, INF_, F1);
    transpose_f16<<<dim3(F2 / 64, F1 / 4), 256, 0, stream>>>(W2, w2t, F1, F2);

    // Layer 1
    mfma_gemm<<<dim3((Nn + 63) / 64, F1 / 128), 256, 0, stream>>>(
        xh, w1t, hh, a_src1, a_dst1, as1, ad1, Nn, INF_);
    passA<<<Nn / 16, 256, 0, stream>>>(poffsets, cursor, as1, ad1, epk, invd1);
    passB1s<<<(Nn / 16) * 4, 256, 0, stream>>>(poffsets, epk, invd1, hh, b1, aggh);

    // Layer 2
    mfma_gemm<<<dim3((Nn + 63) / 64, F2 / 128), 256, 0, stream>>>(
        aggh, w2t, hh, a_src2, a_dst2, as2, ad2, Nn, F1);
    passA<<<Nn / 16, 256, 0, stream>>>(poffsets, cursor, as2, ad2, epk, invd2);
    passB2s<<<(Nn / 16) * 4, 256, 0, stream>>>(poffsets, epk, invd2, hh, tmp);
    reduce4<<<(Nn * OUTC + 255) / 256, 256, 0, stream>>>(tmp, b2, out);
}

// Round 11
// 250.492 us; speedup vs baseline: 1.0957x; 1.0481x over previous
//
#include <hip/hip_runtime.h>
#include <hip/hip_fp16.h>
#include <math.h>
#include <string.h>

#define Nn 10000
#define Ee 320000
#define EE 330000        // E + N self loops
#define EEPS 360064      // padded(4) edge capacity + sentinel
#define INF_ 256
#define HID 128
#define OUTC 128
#define NH 4
#define F1 512
#define F2 512
#define SLOPE 0.2f
#define NB 40            // ceil(Nn/256)

#define CONVX_BLOCKS 10000   // Nn*INF_/256
#define TW1_BLOCKS 512       // (F1/64)*(INF_/4)
#define TW2_BLOCKS 1024      // (F2/64)*(F1/4)

static __device__ __forceinline__ float lrelu(float x) { return fmaxf(x, SLOPE * x); }

using frag_ab = __attribute__((ext_vector_type(8))) _Float16;
using frag_c  = __attribute__((ext_vector_type(4))) float;
typedef _Float16 h2v __attribute__((ext_vector_type(2)));

union U32H2 { unsigned int u; h2v h; };

// ---------------- CSR build (padded-to-4, src scattered into epk.x) ----------------
__global__ void init_counts(int* counts) {
    int i = blockIdx.x * 256 + threadIdx.x;
    if (i < Nn) counts[i] = 1;  // self loop
}

__global__ void count_edges(const int* __restrict__ ei, int* counts) {
    int e = blockIdx.x * 256 + threadIdx.x;
    if (e < Ee) atomicAdd(&counts[ei[Ee + e]], 1);
}

__global__ __launch_bounds__(256) void reduce_counts(const int* __restrict__ counts,
                                                     int* __restrict__ blocksums) {
    __shared__ int sd[256];
    int t = threadIdx.x, i = blockIdx.x * 256 + t;
    int v = (i < Nn) ? ((counts[i] + 3) & ~3) : 0;
    sd[t] = v;
    __syncthreads();
    for (int off = 128; off > 0; off >>= 1) {
        if (t < off) sd[t] += sd[t + off];
        __syncthreads();
    }
    if (t == 0) blocksums[blockIdx.x] = sd[0];
}

__global__ __launch_bounds__(64) void scan_sums(int* blocksums) {
    int t = threadIdx.x;
    int orig = (t < NB) ? blocksums[t] : 0;
    int v = orig;
    for (int off = 1; off < 64; off <<= 1) {
        int u = __shfl_up(v, off);
        if (t >= off) v += u;
    }
    if (t < NB) blocksums[t] = v - orig;  // exclusive
}

// + fused sentinel init (last thread zeroes epk[tp..tp+7])
__global__ __launch_bounds__(256) void scan_final(const int* __restrict__ counts,
                                                  const int* __restrict__ blocksums,
                                                  int* __restrict__ poffsets,
                                                  int* __restrict__ cursor,
                                                  int4* __restrict__ epk) {
    __shared__ int sd[256];
    int t = threadIdx.x, i = blockIdx.x * 256 + t;
    int v = (i < Nn) ? ((counts[i] + 3) & ~3) : 0;
    sd[t] = v;
    __syncthreads();
    int x = v;
    for (int off = 1; off < 256; off <<= 1) {
        int u = (t >= off) ? sd[t - off] : 0;
        __syncthreads();
        x += u;
        sd[t] = x;
        __syncthreads();
    }
    int base = blocksums[blockIdx.x];
    int e = base + x - v;
    if (i < Nn) {
        poffsets[i] = e;
        cursor[i] = e;
        if (i == Nn - 1) {
            int tp = e + v;
            poffsets[Nn] = tp;
#pragma unroll
            for (int j = 0; j < 8; j++) epk[tp + j] = make_int4(0, 0, 0, 0);
        }
    }
}

__global__ void scatter_edges(const int* __restrict__ ei, int* cursor, int4* __restrict__ epk) {
    int t = blockIdx.x * 256 + threadIdx.x;
    if (t >= EE) return;
    int src, dst;
    if (t < Ee) { src = ei[t]; dst = ei[Ee + t]; }
    else        { src = t - Ee; dst = t - Ee; }
    int pos = atomicAdd(&cursor[dst], 1);
    ((int*)epk)[pos * 4] = src;
}

// ---------------- merged fp32->fp16 conversions: x, W1^T, W2^T ----------------
__global__ void convert3(const float* __restrict__ x, const float* __restrict__ W1,
                         const float* __restrict__ W2, _Float16* __restrict__ xh,
                         _Float16* __restrict__ w1t, _Float16* __restrict__ w2t) {
    int b = blockIdx.x, t = threadIdx.x;
    if (b < CONVX_BLOCKS) {
        int i = b * 256 + t;
        xh[i] = (_Float16)x[i];
    } else if (b < CONVX_BLOCKS + TW1_BLOCKS) {
        int bb = b - CONVX_BLOCKS;
        int n = (bb & 7) * 64 + (t & 63);
        int k = (bb >> 3) * 4 + (t >> 6);
        w1t[(size_t)n * INF_ + k] = (_Float16)W1[(size_t)k * F1 + n];
    } else {
        int bb = b - CONVX_BLOCKS - TW1_BLOCKS;
        int n = (bb & 7) * 64 + (t & 63);
        int k = (bb >> 3) * 4 + (t >> 6);
        w2t[(size_t)n * F1 + k] = (_Float16)W2[(size_t)k * F2 + n];
    }
}

// ---------------- MFMA fp16 GEMM + fused alpha dots ----------------
#define LDK 40
__global__ __launch_bounds__(256) void mfma_gemm(const _Float16* __restrict__ A,
                                                 const _Float16* __restrict__ BT,
                                                 _Float16* __restrict__ C,
                                                 const float* __restrict__ a_src,
                                                 const float* __restrict__ a_dst,
                                                 float* __restrict__ as_out,
                                                 float* __restrict__ ad_out,
                                                 int M, int K) {
    __shared__ _Float16 As[64 * LDK];
    __shared__ _Float16 Bs[128 * LDK];
    const int tid = threadIdx.x;
    const int wave = tid >> 6, lane = tid & 63;
    const int q = lane >> 4, ml = lane & 15;
    const int bm = blockIdx.x * 64, bn = blockIdx.y * 128;
    const int head = blockIdx.y;
    const int srow = tid >> 2, scol = (tid & 3) * 8;

    frag_c acc[8];
#pragma unroll
    for (int f = 0; f < 8; f++)
#pragma unroll
        for (int r = 0; r < 4; r++) acc[f][r] = 0.f;

    for (int k0 = 0; k0 < K; k0 += 32) {
        int gm = bm + srow;
        frag_ab av;
        if (gm < M) av = *(const frag_ab*)(A + (size_t)gm * K + k0 + scol);
        else {
#pragma unroll
            for (int j = 0; j < 8; j++) av[j] = (_Float16)0.f;
        }
        *(frag_ab*)&As[srow * LDK + scol] = av;
        *(frag_ab*)&Bs[srow * LDK + scol] =
            *(const frag_ab*)(BT + (size_t)(bn + srow) * K + k0 + scol);
        *(frag_ab*)&Bs[(64 + srow) * LDK + scol] =
            *(const frag_ab*)(BT + (size_t)(bn + 64 + srow) * K + k0 + scol);
        __syncthreads();
        frag_ab a = *(frag_ab*)&As[(wave * 16 + ml) * LDK + q * 8];
#pragma unroll
        for (int f = 0; f < 8; f++) {
            frag_ab b = *(frag_ab*)&Bs[(f * 16 + ml) * LDK + q * 8];
            acc[f] = __builtin_amdgcn_mfma_f32_16x16x32_f16(a, b, acc[f], 0, 0, 0);
        }
        __syncthreads();
    }
    float asum[4] = {}, dsum[4] = {};
#pragma unroll
    for (int f = 0; f < 8; f++) {
        int cl = f * 16 + ml;
        int col = bn + cl;
        float sa = a_src[head * 128 + cl];
        float da = a_dst[head * 128 + cl];
#pragma unroll
        for (int r = 0; r < 4; r++) {
            int row = bm + wave * 16 + q * 4 + r;
            if (row < M) C[(size_t)row * (NH * 128) + col] = (_Float16)acc[f][r];
            asum[r] += acc[f][r] * sa;
            dsum[r] += acc[f][r] * da;
        }
    }
#pragma unroll
    for (int r = 0; r < 4; r++) {
#pragma unroll
        for (int off = 1; off < 16; off <<= 1) {
            asum[r] += __shfl_xor(asum[r], off);
            dsum[r] += __shfl_xor(dsum[r], off);
        }
    }
    if (ml == 0) {
#pragma unroll
        for (int r = 0; r < 4; r++) {
            int row = bm + wave * 16 + q * 4 + r;
            if (row < M) {
                as_out[row * NH + head] = asum[r];
                ad_out[row * NH + head] = dsum[r];
            }
        }
    }
}

// ---------------- pass A: quarter-wave per node; writes packed int4 epk ----------------
__global__ __launch_bounds__(256) void passA(const int* __restrict__ poffsets,
                                             const int* __restrict__ ends,
                                             const float* __restrict__ as,
                                             const float* __restrict__ ad,
                                             int4* __restrict__ epk,
                                             float* __restrict__ invd) {
    int n = blockIdx.x * 16 + (threadIdx.x >> 4);
    int l = threadIdx.x & 15;
    int pstart = poffsets[n], pend = poffsets[n + 1];
    int dend = ends[n];  // pstart + deg
    const int* epx = (const int*)epk;
    float4 adv = *(const float4*)&ad[n * NH];
    float m0 = -1e30f, m1 = -1e30f, m2 = -1e30f, m3 = -1e30f;
    for (int pos = pstart + l; pos < dend; pos += 16) {
        int src = epx[pos * 4];
        float4 asv = *(const float4*)&as[src * NH];
        m0 = fmaxf(m0, lrelu(asv.x + adv.x));
        m1 = fmaxf(m1, lrelu(asv.y + adv.y));
        m2 = fmaxf(m2, lrelu(asv.z + adv.z));
        m3 = fmaxf(m3, lrelu(asv.w + adv.w));
    }
#pragma unroll
    for (int off = 8; off > 0; off >>= 1) {
        m0 = fmaxf(m0, __shfl_xor(m0, off));
        m1 = fmaxf(m1, __shfl_xor(m1, off));
        m2 = fmaxf(m2, __shfl_xor(m2, off));
        m3 = fmaxf(m3, __shfl_xor(m3, off));
    }
    float s0 = 0.f, s1 = 0.f, s2 = 0.f, s3 = 0.f;
    for (int pos = pstart + l; pos < pend; pos += 16) {
        int src = 0;
        float e0 = 0.f, e1 = 0.f, e2 = 0.f, e3 = 0.f;
        if (pos < dend) {
            src = epx[pos * 4];
            float4 asv = *(const float4*)&as[src * NH];
            e0 = __expf(lrelu(asv.x + adv.x) - m0);
            e1 = __expf(lrelu(asv.y + adv.y) - m1);
            e2 = __expf(lrelu(asv.z + adv.z) - m2);
            e3 = __expf(lrelu(asv.w + adv.w) - m3);
        }
        __half2 p01 = __floats2half2_rn(e0, e1);
        __half2 p23 = __floats2half2_rn(e2, e3);
        int w01, w23;
        memcpy(&w01, &p01, 4);
        memcpy(&w23, &p23, 4);
        epk[pos] = make_int4(src, w01, w23, 0);
        s0 += e0; s1 += e1; s2 += e2; s3 += e3;
    }
#pragma unroll
    for (int off = 8; off > 0; off >>= 1) {
        s0 += __shfl_xor(s0, off);
        s1 += __shfl_xor(s1, off);
        s2 += __shfl_xor(s2, off);
        s3 += __shfl_xor(s3, off);
    }
    if (l == 0) {
        *(float4*)&invd[n * NH] = make_float4(1.f / (s0 + 1e-16f), 1.f / (s1 + 1e-16f),
                                              1.f / (s2 + 1e-16f), 1.f / (s3 + 1e-16f));
    }
}

// ---------------- pass B: head-sliced + shuffle-free + 4-edge unroll ----------------
// Block = 16 nodes x 1 head; quarter-wave = one node (16 lanes x 8 ch = 128 ch).
// 4 edges/iter, guard-free (pad-4 + 8-entry sentinel); 8 loads in flight per lane.
__global__ __launch_bounds__(256) void passB1s(const int* __restrict__ poffsets,
                                               const int4* __restrict__ epk,
                                               const float* __restrict__ invd,
                                               const _Float16* __restrict__ hh,
                                               const float* __restrict__ b1,
                                               _Float16* __restrict__ agg) {
    int head = blockIdx.x & 3;
    int nb = (blockIdx.x >> 2) * 16;
    int wave = threadIdx.x >> 6, lane = threadIdx.x & 63;
    int sub = lane >> 4, sl = lane & 15;
    int n = nb + wave * 4 + sub;
    int c = head * 128 + (sl << 3);
    int pstart = poffsets[n], pend = poffsets[n + 1];
    bool hi = (head & 1);
    float acc[8] = {};
    int idx = pstart;
    int4 p0 = epk[idx], p1 = epk[idx + 1], p2 = epk[idx + 2], p3 = epk[idx + 3];
    while (idx < pend) {
        int4 q0 = epk[idx + 4], q1 = epk[idx + 5], q2 = epk[idx + 6], q3 = epk[idx + 7];
        frag_ab r0 = *(const frag_ab*)(hh + (size_t)p0.x * F1 + c);
        frag_ab r1 = *(const frag_ab*)(hh + (size_t)p1.x * F1 + c);
        frag_ab r2 = *(const frag_ab*)(hh + (size_t)p2.x * F1 + c);
        frag_ab r3 = *(const frag_ab*)(hh + (size_t)p3.x * F1 + c);
        U32H2 u0, u1, u2, u3;
        u0.u = (head < 2) ? (unsigned int)p0.y : (unsigned int)p0.z;
        u1.u = (head < 2) ? (unsigned int)p1.y : (unsigned int)p1.z;
        u2.u = (head < 2) ? (unsigned int)p2.y : (unsigned int)p2.z;
        u3.u = (head < 2) ? (unsigned int)p3.y : (unsigned int)p3.z;
        float w0 = hi ? (float)u0.h.y : (float)u0.h.x;
        float w1 = hi ? (float)u1.h.y : (float)u1.h.x;
        float w2 = hi ? (float)u2.h.y : (float)u2.h.x;
        float w3 = hi ? (float)u3.h.y : (float)u3.h.x;
#pragma unroll
        for (int j = 0; j < 8; j++) {
            acc[j] = fmaf((float)r0[j], w0, acc[j]);
            acc[j] = fmaf((float)r1[j], w1, acc[j]);
            acc[j] = fmaf((float)r2[j], w2, acc[j]);
            acc[j] = fmaf((float)r3[j], w3, acc[j]);
        }
        idx += 4; p0 = q0; p1 = q1; p2 = q2; p3 = q3;
    }
    float inv = invd[n * NH + head];
    _Float16 oh[8];
#pragma unroll
    for (int j = 0; j < 8; j++)
        oh[j] = (_Float16)fmaxf(acc[j] * inv + b1[c + j], 0.f);
    *(float4*)&agg[(size_t)n * F1 + c] = *(float4*)oh;
}

__global__ __launch_bounds__(256) void passB2s(const int* __restrict__ poffsets,
                                               const int4* __restrict__ epk,
                                               const float* __restrict__ invd,
                                               const _Float16* __restrict__ hh,
                                               float* __restrict__ tmp) {
    int head = blockIdx.x & 3;
    int nb = (blockIdx.x >> 2) * 16;
    int wave = threadIdx.x >> 6, lane = threadIdx.x & 63;
    int sub = lane >> 4, sl = lane & 15;
    int n = nb + wave * 4 + sub;
    int c = head * 128 + (sl << 3);
    int pstart = poffsets[n], pend = poffsets[n + 1];
    bool hi = (head & 1);
    float acc[8] = {};
    int idx = pstart;
    int4 p0 = epk[idx], p1 = epk[idx + 1], p2 = epk[idx + 2], p3 = epk[idx + 3];
    while (idx < pend) {
        int4 q0 = epk[idx + 4], q1 = epk[idx + 5], q2 = epk[idx + 6], q3 = epk[idx + 7];
        frag_ab r0 = *(const frag_ab*)(hh + (size_t)p0.x * F2 + c);
        frag_ab r1 = *(const frag_ab*)(hh + (size_t)p1.x * F2 + c);
        frag_ab r2 = *(const frag_ab*)(hh + (size_t)p2.x * F2 + c);
        frag_ab r3 = *(const frag_ab*)(hh + (size_t)p3.x * F2 + c);
        U32H2 u0, u1, u2, u3;
        u0.u = (head < 2) ? (unsigned int)p0.y : (unsigned int)p0.z;
        u1.u = (head < 2) ? (unsigned int)p1.y : (unsigned int)p1.z;
        u2.u = (head < 2) ? (unsigned int)p2.y : (unsigned int)p2.z;
        u3.u = (head < 2) ? (unsigned int)p3.y : (unsigned int)p3.z;
        float w0 = hi ? (float)u0.h.y : (float)u0.h.x;
        float w1 = hi ? (float)u1.h.y : (float)u1.h.x;
        float w2 = hi ? (float)u2.h.y : (float)u2.h.x;
        float w3 = hi ? (float)u3.h.y : (float)u3.h.x;
#pragma unroll
        for (int j = 0; j < 8; j++) {
            acc[j] = fmaf((float)r0[j], w0, acc[j]);
            acc[j] = fmaf((float)r1[j], w1, acc[j]);
            acc[j] = fmaf((float)r2[j], w2, acc[j]);
            acc[j] = fmaf((float)r3[j], w3, acc[j]);
        }
        idx += 4; p0 = q0; p1 = q1; p2 = q2; p3 = q3;
    }
    float qq = 0.25f * invd[n * NH + head];
    float* tp = tmp + (size_t)n * F2 + c;   // layout [n][head*128+ch]
    float4 o0 = make_float4(acc[0] * qq, acc[1] * qq, acc[2] * qq, acc[3] * qq);
    float4 o1 = make_float4(acc[4] * qq, acc[5] * qq, acc[6] * qq, acc[7] * qq);
    *(float4*)tp = o0;
    *(float4*)(tp + 4) = o1;
}

// ---------------- reduce 4 heads + bias -> d_out (tmp layout [n][head][128]) ----------------
__global__ void reduce4(const float* __restrict__ tmp, const float* __restrict__ b2,
                        float* __restrict__ out) {
    int i = blockIdx.x * 256 + threadIdx.x;
    if (i >= Nn * OUTC) return;
    int n = i >> 7, oc = i & 127;
    const float* tp = tmp + (size_t)n * 512 + oc;
    out[i] = tp[0] + tp[128] + tp[256] + tp[384] + b2[oc];
}

extern "C" void kernel_launch(void* const* d_in, const int* in_sizes, int n_in,
                              void* d_out, int out_size, void* d_ws, size_t ws_size,
                              hipStream_t stream) {
    const float* x      = (const float*)d_in[0];
    const int*   ei     = (const int*)d_in[1];
    const float* W1     = (const float*)d_in[2];
    const float* a_src1 = (const float*)d_in[3];
    const float* a_dst1 = (const float*)d_in[4];
    const float* b1     = (const float*)d_in[5];
    const float* W2     = (const float*)d_in[6];
    const float* a_src2 = (const float*)d_in[7];
    const float* a_dst2 = (const float*)d_in[8];
    const float* b2     = (const float*)d_in[9];
    float* out = (float*)d_out;

    const size_t NF = (size_t)Nn * F1;
    float* f = (float*)d_ws;
    float* tmp   = f;                    // NF floats [n][head][128]
    float* as1   = tmp + NF;
    float* ad1   = as1 + Nn * NH;
    float* as2   = ad1 + Nn * NH;
    float* ad2   = as2 + Nn * NH;
    float* invd1 = ad2 + Nn * NH;
    float* invd2 = invd1 + Nn * NH;
    int4* epk    = (int4*)(invd2 + Nn * NH);        // EEPS int4
    _Float16* hh   = (_Float16*)(epk + (size_t)EEPS);
    _Float16* aggh = hh + NF;
    _Float16* xh   = aggh + NF;
    _Float16* w1t  = xh + (size_t)Nn * INF_;
    _Float16* w2t  = w1t + (size_t)F1 * INF_;
    int* counts    = (int*)(w2t + (size_t)F2 * F1);
    int* poffsets  = counts + Nn;
    int* cursor    = poffsets + Nn + 1;
    int* blocksums = cursor + Nn;

    // CSR build (padded-to-4; src written straight into epk.x; sentinel fused)
    init_counts<<<(Nn + 255) / 256, 256, 0, stream>>>(counts);
    count_edges<<<(Ee + 255) / 256, 256, 0, stream>>>(ei, counts);
    reduce_counts<<<NB, 256, 0, stream>>>(counts, blocksums);
    scan_sums<<<1, 64, 0, stream>>>(blocksums);
    scan_final<<<NB, 256, 0, stream>>>(counts, blocksums, poffsets, cursor, epk);
    scatter_edges<<<(EE + 255) / 256, 256, 0, stream>>>(ei, cursor, epk);

    // merged fp16 conversions
    convert3<<<CONVX_BLOCKS + TW1_BLOCKS + TW2_BLOCKS, 256, 0, stream>>>(
        x, W1, W2, xh, w1t, w2t);

    // Layer 1
    mfma_gemm<<<dim3((Nn + 63) / 64, F1 / 128), 256, 0, stream>>>(
        xh, w1t, hh, a_src1, a_dst1, as1, ad1, Nn, INF_);
    passA<<<Nn / 16, 256, 0, stream>>>(poffsets, cursor, as1, ad1, epk, invd1);
    passB1s<<<(Nn / 16) * 4, 256, 0, stream>>>(poffsets, epk, invd1, hh, b1, aggh);

    // Layer 2
    mfma_gemm<<<dim3((Nn + 63) / 64, F2 / 128), 256, 0, stream>>>(
        aggh, w2t, hh, a_src2, a_dst2, as2, ad2, Nn, F1);
    passA<<<Nn / 16, 256, 0, stream>>>(poffsets, cursor, as2, ad2, epk, invd2);
    passB2s<<<(Nn / 16) * 4, 256, 0, stream>>>(poffsets, epk, invd2, hh, tmp);
    reduce4<<<(Nn * OUTC + 255) / 256, 256, 0, stream>>>(tmp, b2, out);
}

// Round 12
// 245.269 us; speedup vs baseline: 1.1190x; 1.0213x over previous
//
#include <hip/hip_runtime.h>
#include <hip/hip_fp16.h>
#include <math.h>
#include <string.h>

#define Nn 10000
#define Ee 320000
#define EE 330000        // E + N self loops
#define EEPS 400080      // pad-8 capacity (EE + 7*Nn) + sentinel
#define INF_ 256
#define HID 128
#define OUTC 128
#define NH 4
#define F1 512
#define F2 512
#define SLOPE 0.2f
#define NB 40            // ceil(Nn/256)

#define CONVX_BLOCKS 10000   // Nn*INF_/256
#define TW1_BLOCKS 512       // (F1/64)*(INF_/4)
#define TW2_BLOCKS 1024      // (F2/64)*(F1/4)

static __device__ __forceinline__ float lrelu(float x) { return fmaxf(x, SLOPE * x); }

using frag_ab = __attribute__((ext_vector_type(8))) _Float16;
using frag_c  = __attribute__((ext_vector_type(4))) float;

// ---------------- CSR build (padded-to-8, src scattered into eph[0].x) ----------------
__global__ void init_counts(int* counts) {
    int i = blockIdx.x * 256 + threadIdx.x;
    if (i < Nn) counts[i] = 1;  // self loop
}

__global__ void count_edges(const int* __restrict__ ei, int* counts) {
    int e = blockIdx.x * 256 + threadIdx.x;
    if (e < Ee) atomicAdd(&counts[ei[Ee + e]], 1);
}

__global__ __launch_bounds__(256) void reduce_counts(const int* __restrict__ counts,
                                                     int* __restrict__ blocksums) {
    __shared__ int sd[256];
    int t = threadIdx.x, i = blockIdx.x * 256 + t;
    int v = (i < Nn) ? ((counts[i] + 7) & ~7) : 0;
    sd[t] = v;
    __syncthreads();
    for (int off = 128; off > 0; off >>= 1) {
        if (t < off) sd[t] += sd[t + off];
        __syncthreads();
    }
    if (t == 0) blocksums[blockIdx.x] = sd[0];
}

__global__ __launch_bounds__(64) void scan_sums(int* blocksums) {
    int t = threadIdx.x;
    int orig = (t < NB) ? blocksums[t] : 0;
    int v = orig;
    for (int off = 1; off < 64; off <<= 1) {
        int u = __shfl_up(v, off);
        if (t >= off) v += u;
    }
    if (t < NB) blocksums[t] = v - orig;  // exclusive
}

// + fused sentinel init (last thread zeroes 16 entries in each head array)
__global__ __launch_bounds__(256) void scan_final(const int* __restrict__ counts,
                                                  const int* __restrict__ blocksums,
                                                  int* __restrict__ poffsets,
                                                  int* __restrict__ cursor,
                                                  int2* __restrict__ eph) {
    __shared__ int sd[256];
    int t = threadIdx.x, i = blockIdx.x * 256 + t;
    int v = (i < Nn) ? ((counts[i] + 7) & ~7) : 0;
    sd[t] = v;
    __syncthreads();
    int x = v;
    for (int off = 1; off < 256; off <<= 1) {
        int u = (t >= off) ? sd[t - off] : 0;
        __syncthreads();
        x += u;
        sd[t] = x;
        __syncthreads();
    }
    int base = blocksums[blockIdx.x];
    int e = base + x - v;
    if (i < Nn) {
        poffsets[i] = e;
        cursor[i] = e;
        if (i == Nn - 1) {
            int tp = e + v;
            poffsets[Nn] = tp;
#pragma unroll
            for (int h = 0; h < NH; h++)
#pragma unroll
                for (int j = 0; j < 16; j++)
                    eph[(size_t)h * EEPS + tp + j] = make_int2(0, 0);
        }
    }
}

__global__ void scatter_edges(const int* __restrict__ ei, int* cursor, int2* __restrict__ eph) {
    int t = blockIdx.x * 256 + threadIdx.x;
    if (t >= EE) return;
    int src, dst;
    if (t < Ee) { src = ei[t]; dst = ei[Ee + t]; }
    else        { src = t - Ee; dst = t - Ee; }
    int pos = atomicAdd(&cursor[dst], 1);
    ((int*)eph)[pos * 2] = src;
}

// ---------------- merged fp32->fp16 conversions: x, W1^T, W2^T ----------------
__global__ void convert3(const float* __restrict__ x, const float* __restrict__ W1,
                         const float* __restrict__ W2, _Float16* __restrict__ xh,
                         _Float16* __restrict__ w1t, _Float16* __restrict__ w2t) {
    int b = blockIdx.x, t = threadIdx.x;
    if (b < CONVX_BLOCKS) {
        int i = b * 256 + t;
        xh[i] = (_Float16)x[i];
    } else if (b < CONVX_BLOCKS + TW1_BLOCKS) {
        int bb = b - CONVX_BLOCKS;
        int n = (bb & 7) * 64 + (t & 63);
        int k = (bb >> 3) * 4 + (t >> 6);
        w1t[(size_t)n * INF_ + k] = (_Float16)W1[(size_t)k * F1 + n];
    } else {
        int bb = b - CONVX_BLOCKS - TW1_BLOCKS;
        int n = (bb & 7) * 64 + (t & 63);
        int k = (bb >> 3) * 4 + (t >> 6);
        w2t[(size_t)n * F1 + k] = (_Float16)W2[(size_t)k * F2 + n];
    }
}

// ---------------- MFMA fp16 GEMM + fused alpha dots ----------------
#define LDK 40
__global__ __launch_bounds__(256) void mfma_gemm(const _Float16* __restrict__ A,
                                                 const _Float16* __restrict__ BT,
                                                 _Float16* __restrict__ C,
                                                 const float* __restrict__ a_src,
                                                 const float* __restrict__ a_dst,
                                                 float* __restrict__ as_out,
                                                 float* __restrict__ ad_out,
                                                 int M, int K) {
    __shared__ _Float16 As[64 * LDK];
    __shared__ _Float16 Bs[128 * LDK];
    const int tid = threadIdx.x;
    const int wave = tid >> 6, lane = tid & 63;
    const int q = lane >> 4, ml = lane & 15;
    const int bm = blockIdx.x * 64, bn = blockIdx.y * 128;
    const int head = blockIdx.y;
    const int srow = tid >> 2, scol = (tid & 3) * 8;

    frag_c acc[8];
#pragma unroll
    for (int f = 0; f < 8; f++)
#pragma unroll
        for (int r = 0; r < 4; r++) acc[f][r] = 0.f;

    for (int k0 = 0; k0 < K; k0 += 32) {
        int gm = bm + srow;
        frag_ab av;
        if (gm < M) av = *(const frag_ab*)(A + (size_t)gm * K + k0 + scol);
        else {
#pragma unroll
            for (int j = 0; j < 8; j++) av[j] = (_Float16)0.f;
        }
        *(frag_ab*)&As[srow * LDK + scol] = av;
        *(frag_ab*)&Bs[srow * LDK + scol] =
            *(const frag_ab*)(BT + (size_t)(bn + srow) * K + k0 + scol);
        *(frag_ab*)&Bs[(64 + srow) * LDK + scol] =
            *(const frag_ab*)(BT + (size_t)(bn + 64 + srow) * K + k0 + scol);
        __syncthreads();
        frag_ab a = *(frag_ab*)&As[(wave * 16 + ml) * LDK + q * 8];
#pragma unroll
        for (int f = 0; f < 8; f++) {
            frag_ab b = *(frag_ab*)&Bs[(f * 16 + ml) * LDK + q * 8];
            acc[f] = __builtin_amdgcn_mfma_f32_16x16x32_f16(a, b, acc[f], 0, 0, 0);
        }
        __syncthreads();
    }
    float asum[4] = {}, dsum[4] = {};
#pragma unroll
    for (int f = 0; f < 8; f++) {
        int cl = f * 16 + ml;
        int col = bn + cl;
        float sa = a_src[head * 128 + cl];
        float da = a_dst[head * 128 + cl];
#pragma unroll
        for (int r = 0; r < 4; r++) {
            int row = bm + wave * 16 + q * 4 + r;
            if (row < M) C[(size_t)row * (NH * 128) + col] = (_Float16)acc[f][r];
            asum[r] += acc[f][r] * sa;
            dsum[r] += acc[f][r] * da;
        }
    }
#pragma unroll
    for (int r = 0; r < 4; r++) {
#pragma unroll
        for (int off = 1; off < 16; off <<= 1) {
            asum[r] += __shfl_xor(asum[r], off);
            dsum[r] += __shfl_xor(dsum[r], off);
        }
    }
    if (ml == 0) {
#pragma unroll
        for (int r = 0; r < 4; r++) {
            int row = bm + wave * 16 + q * 4 + r;
            if (row < M) {
                as_out[row * NH + head] = asum[r];
                ad_out[row * NH + head] = dsum[r];
            }
        }
    }
}

// ---------------- pass A: quarter-wave per node; reg-cached gathers; per-head writes ----------------
__global__ __launch_bounds__(256) void passA(const int* __restrict__ poffsets,
                                             const int* __restrict__ ends,
                                             const float* __restrict__ as,
                                             const float* __restrict__ ad,
                                             int2* __restrict__ eph,
                                             float* __restrict__ invd) {
    int n = blockIdx.x * 16 + (threadIdx.x >> 4);
    int l = threadIdx.x & 15;
    int pstart = poffsets[n], pend = poffsets[n + 1];
    int dend = ends[n];                 // pstart + deg
    int deg = dend - pstart, pdeg = pend - pstart;
    const int* epx = (const int*)eph;   // head-0 array holds src after scatter
    float4 adv = *(const float4*)&ad[n * NH];
    float m0 = -1e30f, m1 = -1e30f, m2 = -1e30f, m3 = -1e30f;
    float4 cav[3];
    int csrc[3];
    int nc = 0;
    for (int k = l; k < deg; k += 16) {
        int src = epx[(pstart + k) * 2];
        float4 asv = *(const float4*)&as[src * NH];
        if (nc < 3) { cav[nc] = asv; csrc[nc] = src; nc++; }
        m0 = fmaxf(m0, lrelu(asv.x + adv.x));
        m1 = fmaxf(m1, lrelu(asv.y + adv.y));
        m2 = fmaxf(m2, lrelu(asv.z + adv.z));
        m3 = fmaxf(m3, lrelu(asv.w + adv.w));
    }
#pragma unroll
    for (int off = 8; off > 0; off >>= 1) {
        m0 = fmaxf(m0, __shfl_xor(m0, off));
        m1 = fmaxf(m1, __shfl_xor(m1, off));
        m2 = fmaxf(m2, __shfl_xor(m2, off));
        m3 = fmaxf(m3, __shfl_xor(m3, off));
    }
    float s0 = 0.f, s1 = 0.f, s2 = 0.f, s3 = 0.f;
    int trip = 0;
    for (int k = l; k < pdeg; k += 16, trip++) {
        int src = 0;
        float e0 = 0.f, e1 = 0.f, e2 = 0.f, e3 = 0.f;
        if (k < deg) {
            float4 asv;
            if (trip < nc) { asv = cav[trip]; src = csrc[trip]; }
            else {
                src = epx[(pstart + k) * 2];
                asv = *(const float4*)&as[src * NH];
            }
            e0 = __expf(lrelu(asv.x + adv.x) - m0);
            e1 = __expf(lrelu(asv.y + adv.y) - m1);
            e2 = __expf(lrelu(asv.z + adv.z) - m2);
            e3 = __expf(lrelu(asv.w + adv.w) - m3);
        }
        int pos = pstart + k;
        eph[pos] = make_int2(src, __float_as_int(e0));
        eph[EEPS + pos] = make_int2(src, __float_as_int(e1));
        eph[2 * EEPS + pos] = make_int2(src, __float_as_int(e2));
        eph[3 * EEPS + pos] = make_int2(src, __float_as_int(e3));
        s0 += e0; s1 += e1; s2 += e2; s3 += e3;
    }
#pragma unroll
    for (int off = 8; off > 0; off >>= 1) {
        s0 += __shfl_xor(s0, off);
        s1 += __shfl_xor(s1, off);
        s2 += __shfl_xor(s2, off);
        s3 += __shfl_xor(s3, off);
    }
    if (l == 0) {
        *(float4*)&invd[n * NH] = make_float4(1.f / (s0 + 1e-16f), 1.f / (s1 + 1e-16f),
                                              1.f / (s2 + 1e-16f), 1.f / (s3 + 1e-16f));
    }
}

// ---------------- pass B: head-sliced + shuffle-free + 8-edge unroll ----------------
// Block = 16 nodes x 1 head; quarter-wave = one node (16 lanes x 8 ch = 128 ch).
// 8 edges/iter, guard-free (pad-8 + 16-entry sentinel); 16 loads in flight/lane.
__global__ __launch_bounds__(256) void passB1s(const int* __restrict__ poffsets,
                                               const int2* __restrict__ eph,
                                               const float* __restrict__ invd,
                                               const _Float16* __restrict__ hh,
                                               const float* __restrict__ b1,
                                               _Float16* __restrict__ agg) {
    int head = blockIdx.x & 3;
    int nb = (blockIdx.x >> 2) * 16;
    int wave = threadIdx.x >> 6, lane = threadIdx.x & 63;
    int sub = lane >> 4, sl = lane & 15;
    int n = nb + wave * 4 + sub;
    int c = head * 128 + (sl << 3);
    int pstart = poffsets[n], pend = poffsets[n + 1];
    const int2* ep = eph + (size_t)head * EEPS;
    float acc[8] = {};
    int idx = pstart;
    int2 p[8];
#pragma unroll
    for (int j = 0; j < 8; j++) p[j] = ep[idx + j];
    while (idx < pend) {
        int2 q[8];
#pragma unroll
        for (int j = 0; j < 8; j++) q[j] = ep[idx + 8 + j];
#pragma unroll
        for (int j = 0; j < 8; j++) {
            float w = __int_as_float(p[j].y);
            frag_ab r = *(const frag_ab*)(hh + (size_t)p[j].x * F1 + c);
#pragma unroll
            for (int u = 0; u < 8; u++) acc[u] = fmaf((float)r[u], w, acc[u]);
        }
        idx += 8;
#pragma unroll
        for (int j = 0; j < 8; j++) p[j] = q[j];
    }
    float inv = invd[n * NH + head];
    _Float16 oh[8];
#pragma unroll
    for (int j = 0; j < 8; j++)
        oh[j] = (_Float16)fmaxf(acc[j] * inv + b1[c + j], 0.f);
    *(float4*)&agg[(size_t)n * F1 + c] = *(float4*)oh;
}

__global__ __launch_bounds__(256) void passB2s(const int* __restrict__ poffsets,
                                               const int2* __restrict__ eph,
                                               const float* __restrict__ invd,
                                               const _Float16* __restrict__ hh,
                                               float* __restrict__ tmp) {
    int head = blockIdx.x & 3;
    int nb = (blockIdx.x >> 2) * 16;
    int wave = threadIdx.x >> 6, lane = threadIdx.x & 63;
    int sub = lane >> 4, sl = lane & 15;
    int n = nb + wave * 4 + sub;
    int c = head * 128 + (sl << 3);
    int pstart = poffsets[n], pend = poffsets[n + 1];
    const int2* ep = eph + (size_t)head * EEPS;
    float acc[8] = {};
    int idx = pstart;
    int2 p[8];
#pragma unroll
    for (int j = 0; j < 8; j++) p[j] = ep[idx + j];
    while (idx < pend) {
        int2 q[8];
#pragma unroll
        for (int j = 0; j < 8; j++) q[j] = ep[idx + 8 + j];
#pragma unroll
        for (int j = 0; j < 8; j++) {
            float w = __int_as_float(p[j].y);
            frag_ab r = *(const frag_ab*)(hh + (size_t)p[j].x * F2 + c);
#pragma unroll
            for (int u = 0; u < 8; u++) acc[u] = fmaf((float)r[u], w, acc[u]);
        }
        idx += 8;
#pragma unroll
        for (int j = 0; j < 8; j++) p[j] = q[j];
    }
    float qq = 0.25f * invd[n * NH + head];
    float* tp = tmp + (size_t)n * F2 + c;   // layout [n][head*128+ch]
    float4 o0 = make_float4(acc[0] * qq, acc[1] * qq, acc[2] * qq, acc[3] * qq);
    float4 o1 = make_float4(acc[4] * qq, acc[5] * qq, acc[6] * qq, acc[7] * qq);
    *(float4*)tp = o0;
    *(float4*)(tp + 4) = o1;
}

// ---------------- reduce 4 heads + bias -> d_out (tmp layout [n][head][128]) ----------------
__global__ void reduce4(const float* __restrict__ tmp, const float* __restrict__ b2,
                        float* __restrict__ out) {
    int i = blockIdx.x * 256 + threadIdx.x;
    if (i >= Nn * OUTC) return;
    int n = i >> 7, oc = i & 127;
    const float* tp = tmp + (size_t)n * 512 + oc;
    out[i] = tp[0] + tp[128] + tp[256] + tp[384] + b2[oc];
}

extern "C" void kernel_launch(void* const* d_in, const int* in_sizes, int n_in,
                              void* d_out, int out_size, void* d_ws, size_t ws_size,
                              hipStream_t stream) {
    const float* x      = (const float*)d_in[0];
    const int*   ei     = (const int*)d_in[1];
    const float* W1     = (const float*)d_in[2];
    const float* a_src1 = (const float*)d_in[3];
    const float* a_dst1 = (const float*)d_in[4];
    const float* b1     = (const float*)d_in[5];
    const float* W2     = (const float*)d_in[6];
    const float* a_src2 = (const float*)d_in[7];
    const float* a_dst2 = (const float*)d_in[8];
    const float* b2     = (const float*)d_in[9];
    float* out = (float*)d_out;

    const size_t NF = (size_t)Nn * F1;
    float* f = (float*)d_ws;
    float* tmp   = f;                    // NF floats [n][head][128]
    float* as1   = tmp + NF;
    float* ad1   = as1 + Nn * NH;
    float* as2   = ad1 + Nn * NH;
    float* ad2   = as2 + Nn * NH;
    float* invd1 = ad2 + Nn * NH;
    float* invd2 = invd1 + Nn * NH;
    int2* eph    = (int2*)(invd2 + Nn * NH);        // NH*EEPS int2 [head][edge]=(src,w)
    _Float16* hh   = (_Float16*)(eph + (size_t)NH * EEPS);
    _Float16* aggh = hh + NF;
    _Float16* xh   = aggh + NF;
    _Float16* w1t  = xh + (size_t)Nn * INF_;
    _Float16* w2t  = w1t + (size_t)F1 * INF_;
    int* counts    = (int*)(w2t + (size_t)F2 * F1);
    int* poffsets  = counts + Nn;
    int* cursor    = poffsets + Nn + 1;
    int* blocksums = cursor + Nn;

    // CSR build (pad-8; src written straight into eph[0].x; sentinel fused)
    init_counts<<<(Nn + 255) / 256, 256, 0, stream>>>(counts);
    count_edges<<<(Ee + 255) / 256, 256, 0, stream>>>(ei, counts);
    reduce_counts<<<NB, 256, 0, stream>>>(counts, blocksums);
    scan_sums<<<1, 64, 0, stream>>>(blocksums);
    scan_final<<<NB, 256, 0, stream>>>(counts, blocksums, poffsets, cursor, eph);
    scatter_edges<<<(EE + 255) / 256, 256, 0, stream>>>(ei, cursor, eph);

    // merged fp16 conversions
    convert3<<<CONVX_BLOCKS + TW1_BLOCKS + TW2_BLOCKS, 256, 0, stream>>>(
        x, W1, W2, xh, w1t, w2t);

    // Layer 1
    mfma_gemm<<<dim3((Nn + 63) / 64, F1 / 128), 256, 0, stream>>>(
        xh, w1t, hh, a_src1, a_dst1, as1, ad1, Nn, INF_);
    passA<<<Nn / 16, 256, 0, stream>>>(poffsets, cursor, as1, ad1, eph, invd1);
    passB1s<<<(Nn / 16) * 4, 256, 0, stream>>>(poffsets, eph, invd1, hh, b1, aggh);

    // Layer 2
    mfma_gemm<<<dim3((Nn + 63) / 64, F2 / 128), 256, 0, stream>>>(
        aggh, w2t, hh, a_src2, a_dst2, as2, ad2, Nn, F1);
    passA<<<Nn / 16, 256, 0, stream>>>(poffsets, cursor, as2, ad2, eph, invd2);
    passB2s<<<(Nn / 16) * 4, 256, 0, stream>>>(poffsets, eph, invd2, hh, tmp);
    reduce4<<<(Nn * OUTC + 255) / 256, 256, 0, stream>>>(tmp, b2, out);
}

// Round 14
// 244.042 us; speedup vs baseline: 1.1246x; 1.0050x over previous
//
#include <hip/hip_runtime.h>
#include <hip/hip_fp16.h>
#include <math.h>

#define Nn 10000
#define Ee 320000
#define EE 330000        // E + N self loops
#define EEPS 400080      // pad-8 capacity
#define INF_ 256
#define NH 4
#define OUTC 128
#define F1 512
#define F2 512
#define SLOPE 0.2f
#define NB 40            // ceil(Nn/256)
#define CAP 128          // LDS edge cache per node

#define SC_BLOCKS 1290       // ceil(EE/256)
#define CONVX_BLOCKS 10000   // Nn*INF_/256
#define TW1_BLOCKS 512       // (F1/64)*(INF_/4)
#define TW2_BLOCKS 1024      // (F2/64)*(F1/4)

static __device__ __forceinline__ float lrelu(float x) { return fmaxf(x, SLOPE * x); }

using frag_ab = __attribute__((ext_vector_type(8))) _Float16;
using frag_c  = __attribute__((ext_vector_type(4))) float;

// ---------------- CSR build (counts zeroed by memset; self-loop = +1 in scan) ----------------
__global__ void count_edges(const int* __restrict__ ei, int* counts) {
    int e = blockIdx.x * 256 + threadIdx.x;
    if (e < Ee) atomicAdd(&counts[ei[Ee + e]], 1);
}

__global__ __launch_bounds__(256) void reduce_counts(const int* __restrict__ counts,
                                                     int* __restrict__ blocksums) {
    __shared__ int sd[256];
    int t = threadIdx.x, i = blockIdx.x * 256 + t;
    int v = (i < Nn) ? ((counts[i] + 8) & ~7) : 0;   // (+1 self loop, pad 8)
    sd[t] = v;
    __syncthreads();
    for (int off = 128; off > 0; off >>= 1) {
        if (t < off) sd[t] += sd[t + off];
        __syncthreads();
    }
    if (t == 0) blocksums[blockIdx.x] = sd[0];
}

__global__ __launch_bounds__(64) void scan_sums(int* blocksums) {
    int t = threadIdx.x;
    int orig = (t < NB) ? blocksums[t] : 0;
    int v = orig;
    for (int off = 1; off < 64; off <<= 1) {
        int u = __shfl_up(v, off);
        if (t >= off) v += u;
    }
    if (t < NB) blocksums[t] = v - orig;  // exclusive
}

__global__ __launch_bounds__(256) void scan_final(const int* __restrict__ counts,
                                                  const int* __restrict__ blocksums,
                                                  int* __restrict__ poffsets,
                                                  int* __restrict__ cursor) {
    __shared__ int sd[256];
    int t = threadIdx.x, i = blockIdx.x * 256 + t;
    int v = (i < Nn) ? ((counts[i] + 8) & ~7) : 0;
    sd[t] = v;
    __syncthreads();
    int x = v;
    for (int off = 1; off < 256; off <<= 1) {
        int u = (t >= off) ? sd[t - off] : 0;
        __syncthreads();
        x += u;
        sd[t] = x;
        __syncthreads();
    }
    int base = blocksums[blockIdx.x];
    int e = base + x - v;
    if (i < Nn) {
        poffsets[i] = e;
        cursor[i] = e;
        if (i == Nn - 1) poffsets[Nn] = e + v;
    }
}

// ---------------- prep: scatter edges + fp16 conversions in one launch ----------------
__global__ void prep(const int* __restrict__ ei, int* cursor, int* __restrict__ csr,
                     const float* __restrict__ x, const float* __restrict__ W1,
                     const float* __restrict__ W2, _Float16* __restrict__ xh,
                     _Float16* __restrict__ w1t, _Float16* __restrict__ w2t) {
    int b = blockIdx.x, t = threadIdx.x;
    if (b < SC_BLOCKS) {
        int e = b * 256 + t;
        if (e < EE) {
            int src, dst;
            if (e < Ee) { src = ei[e]; dst = ei[Ee + e]; }
            else        { src = e - Ee; dst = e - Ee; }
            int pos = atomicAdd(&cursor[dst], 1);
            csr[pos] = src;
        }
    } else if (b < SC_BLOCKS + CONVX_BLOCKS) {
        int i = (b - SC_BLOCKS) * 256 + t;
        xh[i] = (_Float16)x[i];
    } else if (b < SC_BLOCKS + CONVX_BLOCKS + TW1_BLOCKS) {
        int bb = b - SC_BLOCKS - CONVX_BLOCKS;
        int n = (bb & 7) * 64 + (t & 63);
        int k = (bb >> 3) * 4 + (t >> 6);
        w1t[(size_t)n * INF_ + k] = (_Float16)W1[(size_t)k * F1 + n];
    } else {
        int bb = b - SC_BLOCKS - CONVX_BLOCKS - TW1_BLOCKS;
        int n = (bb & 7) * 64 + (t & 63);
        int k = (bb >> 3) * 4 + (t >> 6);
        w2t[(size_t)n * F1 + k] = (_Float16)W2[(size_t)k * F2 + n];
    }
}

// ---------------- MFMA fp16 GEMM + fused alpha dots ----------------
#define LDK 40
__global__ __launch_bounds__(256) void mfma_gemm(const _Float16* __restrict__ A,
                                                 const _Float16* __restrict__ BT,
                                                 _Float16* __restrict__ C,
                                                 const float* __restrict__ a_src,
                                                 const float* __restrict__ a_dst,
                                                 float* __restrict__ as_out,
                                                 float* __restrict__ ad_out,
                                                 int M, int K) {
    __shared__ _Float16 As[64 * LDK];
    __shared__ _Float16 Bs[128 * LDK];
    const int tid = threadIdx.x;
    const int wave = tid >> 6, lane = tid & 63;
    const int q = lane >> 4, ml = lane & 15;
    const int bm = blockIdx.x * 64, bn = blockIdx.y * 128;
    const int head = blockIdx.y;
    const int srow = tid >> 2, scol = (tid & 3) * 8;

    frag_c acc[8];
#pragma unroll
    for (int f = 0; f < 8; f++)
#pragma unroll
        for (int r = 0; r < 4; r++) acc[f][r] = 0.f;

    for (int k0 = 0; k0 < K; k0 += 32) {
        int gm = bm + srow;
        frag_ab av;
        if (gm < M) av = *(const frag_ab*)(A + (size_t)gm * K + k0 + scol);
        else {
#pragma unroll
            for (int j = 0; j < 8; j++) av[j] = (_Float16)0.f;
        }
        *(frag_ab*)&As[srow * LDK + scol] = av;
        *(frag_ab*)&Bs[srow * LDK + scol] =
            *(const frag_ab*)(BT + (size_t)(bn + srow) * K + k0 + scol);
        *(frag_ab*)&Bs[(64 + srow) * LDK + scol] =
            *(const frag_ab*)(BT + (size_t)(bn + 64 + srow) * K + k0 + scol);
        __syncthreads();
        frag_ab a = *(frag_ab*)&As[(wave * 16 + ml) * LDK + q * 8];
#pragma unroll
        for (int f = 0; f < 8; f++) {
            frag_ab b = *(frag_ab*)&Bs[(f * 16 + ml) * LDK + q * 8];
            acc[f] = __builtin_amdgcn_mfma_f32_16x16x32_f16(a, b, acc[f], 0, 0, 0);
        }
        __syncthreads();
    }
    float asum[4] = {}, dsum[4] = {};
#pragma unroll
    for (int f = 0; f < 8; f++) {
        int cl = f * 16 + ml;
        int col = bn + cl;
        float sa = a_src[head * 128 + cl];
        float da = a_dst[head * 128 + cl];
#pragma unroll
        for (int r = 0; r < 4; r++) {
            int row = bm + wave * 16 + q * 4 + r;
            if (row < M) C[(size_t)row * (NH * 128) + col] = (_Float16)acc[f][r];
            asum[r] += acc[f][r] * sa;
            dsum[r] += acc[f][r] * da;
        }
    }
#pragma unroll
    for (int r = 0; r < 4; r++) {
#pragma unroll
        for (int off = 1; off < 16; off <<= 1) {
            asum[r] += __shfl_xor(asum[r], off);
            dsum[r] += __shfl_xor(dsum[r], off);
        }
    }
    if (ml == 0) {
#pragma unroll
        for (int r = 0; r < 4; r++) {
            int row = bm + wave * 16 + q * 4 + r;
            if (row < M) {
                as_out[row * NH + head] = asum[r];
                ad_out[row * NH + head] = dsum[r];
            }
        }
    }
}

// ---------------- fused softmax + aggregation, layer 1 ----------------
// Block = 16 nodes x 1 head (head = blockIdx&3 -> XCD slice, 2.56 MB L2-resident).
// Quarter-wave = one node. Phase 1: per-head softmax, (src,w) -> LDS (CAP=128).
// Phase 2: shuffle-free 8-edge-unroll aggregation from LDS; overflow recomputed.
__global__ __launch_bounds__(256) void passAB1(const int* __restrict__ poffsets,
                                               const int* __restrict__ ends,
                                               const int* __restrict__ csr,
                                               const float* __restrict__ as,
                                               const float* __restrict__ ad,
                                               const _Float16* __restrict__ hh,
                                               const float* __restrict__ b1,
                                               _Float16* __restrict__ agg) {
    __shared__ int2 ew[16][CAP];
    int head = blockIdx.x & 3;
    int qw = threadIdx.x >> 4;
    int l = threadIdx.x & 15;
    int n = (blockIdx.x >> 2) * 16 + qw;
    int pstart = poffsets[n], pend = poffsets[n + 1];
    int deg = ends[n] - pstart;
    int pdeg = pend - pstart;
    float adh = ad[n * NH + head];
    float m = -1e30f;
    for (int k = l; k < deg; k += 16) {
        int src = csr[pstart + k];
        m = fmaxf(m, lrelu(as[src * NH + head] + adh));
    }
    m = fmaxf(m, __shfl_xor(m, 1));
    m = fmaxf(m, __shfl_xor(m, 2));
    m = fmaxf(m, __shfl_xor(m, 4));
    m = fmaxf(m, __shfl_xor(m, 8));
    float s = 0.f;
    for (int k = l; k < pdeg; k += 16) {
        int src = 0;
        float e = 0.f;
        if (k < deg) {
            src = csr[pstart + k];
            e = __expf(lrelu(as[src * NH + head] + adh) - m);
        }
        if (k < CAP) ew[qw][k] = make_int2(src, __float_as_int(e));
        s += e;
    }
    s += __shfl_xor(s, 1);
    s += __shfl_xor(s, 2);
    s += __shfl_xor(s, 4);
    s += __shfl_xor(s, 8);
    float inv = 1.f / (s + 1e-16f);
    __syncthreads();
    int c = head * 128 + (l << 3);
    float acc[8] = {};
    int lim = pdeg < CAP ? pdeg : CAP;
    for (int kk = 0; kk < lim; kk += 8) {
        int2 p[8];
#pragma unroll
        for (int j = 0; j < 8; j++) p[j] = ew[qw][kk + j];
#pragma unroll
        for (int j = 0; j < 8; j++) {
            float w = __int_as_float(p[j].y);
            frag_ab r = *(const frag_ab*)(hh + (size_t)p[j].x * F1 + c);
#pragma unroll
            for (int u = 0; u < 8; u++) acc[u] = fmaf((float)r[u], w, acc[u]);
        }
    }
    for (int kk = CAP; kk < pdeg; kk += 8) {   // rare overflow
#pragma unroll
        for (int j = 0; j < 8; j++) {
            int k = kk + j;
            int src = 0;
            float e = 0.f;
            if (k < deg) {
                src = csr[pstart + k];
                e = __expf(lrelu(as[src * NH + head] + adh) - m);
            }
            frag_ab r = *(const frag_ab*)(hh + (size_t)src * F1 + c);
#pragma unroll
            for (int u = 0; u < 8; u++) acc[u] = fmaf((float)r[u], e, acc[u]);
        }
    }
    _Float16 oh[8];
#pragma unroll
    for (int j = 0; j < 8; j++)
        oh[j] = (_Float16)fmaxf(acc[j] * inv + b1[c + j], 0.f);
    *(float4*)&agg[(size_t)n * F1 + c] = *(float4*)oh;
}

// ---------------- fused softmax + aggregation, layer 2 -> tmp ----------------
__global__ __launch_bounds__(256) void passAB2(const int* __restrict__ poffsets,
                                               const int* __restrict__ ends,
                                               const int* __restrict__ csr,
                                               const float* __restrict__ as,
                                               const float* __restrict__ ad,
                                               const _Float16* __restrict__ hh,
                                               float* __restrict__ tmp) {
    __shared__ int2 ew[16][CAP];
    int head = blockIdx.x & 3;
    int qw = threadIdx.x >> 4;
    int l = threadIdx.x & 15;
    int n = (blockIdx.x >> 2) * 16 + qw;
    int pstart = poffsets[n], pend = poffsets[n + 1];
    int deg = ends[n] - pstart;
    int pdeg = pend - pstart;
    float adh = ad[n * NH + head];
    float m = -1e30f;
    for (int k = l; k < deg; k += 16) {
        int src = csr[pstart + k];
        m = fmaxf(m, lrelu(as[src * NH + head] + adh));
    }
    m = fmaxf(m, __shfl_xor(m, 1));
    m = fmaxf(m, __shfl_xor(m, 2));
    m = fmaxf(m, __shfl_xor(m, 4));
    m = fmaxf(m, __shfl_xor(m, 8));
    float s = 0.f;
    for (int k = l; k < pdeg; k += 16) {
        int src = 0;
        float e = 0.f;
        if (k < deg) {
            src = csr[pstart + k];
            e = __expf(lrelu(as[src * NH + head] + adh) - m);
        }
        if (k < CAP) ew[qw][k] = make_int2(src, __float_as_int(e));
        s += e;
    }
    s += __shfl_xor(s, 1);
    s += __shfl_xor(s, 2);
    s += __shfl_xor(s, 4);
    s += __shfl_xor(s, 8);
    float inv = 1.f / (s + 1e-16f);
    __syncthreads();
    int c = head * 128 + (l << 3);
    float acc[8] = {};
    int lim = pdeg < CAP ? pdeg : CAP;
    for (int kk = 0; kk < lim; kk += 8) {
        int2 p[8];
#pragma unroll
        for (int j = 0; j < 8; j++) p[j] = ew[qw][kk + j];
#pragma unroll
        for (int j = 0; j < 8; j++) {
            float w = __int_as_float(p[j].y);
            frag_ab r = *(const frag_ab*)(hh + (size_t)p[j].x * F2 + c);
#pragma unroll
            for (int u = 0; u < 8; u++) acc[u] = fmaf((float)r[u], w, acc[u]);
        }
    }
    for (int kk = CAP; kk < pdeg; kk += 8) {
#pragma unroll
        for (int j = 0; j < 8; j++) {
            int k = kk + j;
            int src = 0;
            float e = 0.f;
            if (k < deg) {
                src = csr[pstart + k];
                e = __expf(lrelu(as[src * NH + head] + adh) - m);
            }
            frag_ab r = *(const frag_ab*)(hh + (size_t)src * F2 + c);
#pragma unroll
            for (int u = 0; u < 8; u++) acc[u] = fmaf((float)r[u], e, acc[u]);
        }
    }
    float qq = 0.25f * inv;
    float* tp = tmp + (size_t)n * F2 + c;   // layout [n][head*128+ch]
    float4 o0 = make_float4(acc[0] * qq, acc[1] * qq, acc[2] * qq, acc[3] * qq);
    float4 o1 = make_float4(acc[4] * qq, acc[5] * qq, acc[6] * qq, acc[7] * qq);
    *(float4*)tp = o0;
    *(float4*)(tp + 4) = o1;
}

// ---------------- reduce 4 heads + bias -> d_out (tmp layout [n][head][128]) ----------------
__global__ void reduce4(const float* __restrict__ tmp, const float* __restrict__ b2,
                        float* __restrict__ out) {
    int i = blockIdx.x * 256 + threadIdx.x;
    if (i >= Nn * OUTC) return;
    int n = i >> 7, oc = i & 127;
    const float* tp = tmp + (size_t)n * 512 + oc;
    out[i] = tp[0] + tp[128] + tp[256] + tp[384] + b2[oc];
}

extern "C" void kernel_launch(void* const* d_in, const int* in_sizes, int n_in,
                              void* d_out, int out_size, void* d_ws, size_t ws_size,
                              hipStream_t stream) {
    const float* x      = (const float*)d_in[0];
    const int*   ei     = (const int*)d_in[1];
    const float* W1     = (const float*)d_in[2];
    const float* a_src1 = (const float*)d_in[3];
    const float* a_dst1 = (const float*)d_in[4];
    const float* b1     = (const float*)d_in[5];
    const float* W2     = (const float*)d_in[6];
    const float* a_src2 = (const float*)d_in[7];
    const float* a_dst2 = (const float*)d_in[8];
    const float* b2     = (const float*)d_in[9];
    float* out = (float*)d_out;

    const size_t NF = (size_t)Nn * F1;
    float* f = (float*)d_ws;
    float* tmp   = f;                    // NF floats [n][head][128]
    float* as1   = tmp + NF;
    float* ad1   = as1 + Nn * NH;
    float* as2   = ad1 + Nn * NH;
    float* ad2   = as2 + Nn * NH;
    int* csr     = (int*)(ad2 + Nn * NH);            // EEPS ints (pad-8)
    _Float16* hh   = (_Float16*)(csr + EEPS);
    _Float16* aggh = hh + NF;
    _Float16* xh   = aggh + NF;
    _Float16* w1t  = xh + (size_t)Nn * INF_;
    _Float16* w2t  = w1t + (size_t)F1 * INF_;
    int* counts    = (int*)(w2t + (size_t)F2 * F1);
    int* poffsets  = counts + Nn;
    int* cursor    = poffsets + Nn + 1;
    int* blocksums = cursor + Nn;

    // CSR build: memset counts, count edges, scan (+1 self loop, pad-8)
    (void)hipMemsetAsync(counts, 0, Nn * sizeof(int), stream);
    count_edges<<<(Ee + 255) / 256, 256, 0, stream>>>(ei, counts);
    reduce_counts<<<NB, 256, 0, stream>>>(counts, blocksums);
    scan_sums<<<1, 64, 0, stream>>>(blocksums);
    scan_final<<<NB, 256, 0, stream>>>(counts, blocksums, poffsets, cursor);

    // scatter + fp16 conversions, one launch
    prep<<<SC_BLOCKS + CONVX_BLOCKS + TW1_BLOCKS + TW2_BLOCKS, 256, 0, stream>>>(
        ei, cursor, csr, x, W1, W2, xh, w1t, w2t);

    // Layer 1
    mfma_gemm<<<dim3((Nn + 63) / 64, F1 / 128), 256, 0, stream>>>(
        xh, w1t, hh, a_src1, a_dst1, as1, ad1, Nn, INF_);
    passAB1<<<(Nn / 16) * 4, 256, 0, stream>>>(poffsets, cursor, csr, as1, ad1, hh, b1, aggh);

    // Layer 2
    mfma_gemm<<<dim3((Nn + 63) / 64, F2 / 128), 256, 0, stream>>>(
        aggh, w2t, hh, a_src2, a_dst2, as2, ad2, Nn, F1);
    passAB2<<<(Nn / 16) * 4, 256, 0, stream>>>(poffsets, cursor, csr, as2, ad2, hh, tmp);
    reduce4<<<(Nn * OUTC + 255) / 256, 256, 0, stream>>>(tmp, b2, out);
}

// Round 15
// 243.993 us; speedup vs baseline: 1.1249x; 1.0002x over previous
//
#include <hip/hip_runtime.h>
#include <hip/hip_fp16.h>
#include <math.h>

#define Nn 10000
#define Ee 320000
#define EE 330000        // E + N self loops
#define EEPS 400080      // pad-8 capacity
#define INF_ 256
#define NH 4
#define OUTC 128
#define F1 512
#define F2 512
#define SLOPE 0.2f
#define NB 40            // ceil(Nn/256)
#define CAP 64           // LDS edge cache per node (P(deg>63) ~ 6e-8; overflow path covers)

#define SC_BLOCKS 1290       // ceil(EE/256)
#define CONVX_BLOCKS 10000   // Nn*INF_/256
#define TW1_BLOCKS 512       // (F1/64)*(INF_/4)
#define TW2_BLOCKS 1024      // (F2/64)*(F1/4)

static __device__ __forceinline__ float lrelu(float x) { return fmaxf(x, SLOPE * x); }

using frag_ab = __attribute__((ext_vector_type(8))) _Float16;
using frag_c  = __attribute__((ext_vector_type(4))) float;

// ---------------- CSR build (counts zeroed by memset; self-loop = +1 in scan) ----------------
__global__ void count_edges(const int* __restrict__ ei, int* counts) {
    int e = blockIdx.x * 256 + threadIdx.x;
    if (e < Ee) atomicAdd(&counts[ei[Ee + e]], 1);
}

__global__ __launch_bounds__(256) void reduce_counts(const int* __restrict__ counts,
                                                     int* __restrict__ blocksums) {
    __shared__ int sd[256];
    int t = threadIdx.x, i = blockIdx.x * 256 + t;
    int v = (i < Nn) ? ((counts[i] + 8) & ~7) : 0;   // (+1 self loop, pad 8)
    sd[t] = v;
    __syncthreads();
    for (int off = 128; off > 0; off >>= 1) {
        if (t < off) sd[t] += sd[t + off];
        __syncthreads();
    }
    if (t == 0) blocksums[blockIdx.x] = sd[0];
}

__global__ __launch_bounds__(64) void scan_sums(int* blocksums) {
    int t = threadIdx.x;
    int orig = (t < NB) ? blocksums[t] : 0;
    int v = orig;
    for (int off = 1; off < 64; off <<= 1) {
        int u = __shfl_up(v, off);
        if (t >= off) v += u;
    }
    if (t < NB) blocksums[t] = v - orig;  // exclusive
}

__global__ __launch_bounds__(256) void scan_final(const int* __restrict__ counts,
                                                  const int* __restrict__ blocksums,
                                                  int* __restrict__ poffsets,
                                                  int* __restrict__ cursor) {
    __shared__ int sd[256];
    int t = threadIdx.x, i = blockIdx.x * 256 + t;
    int v = (i < Nn) ? ((counts[i] + 8) & ~7) : 0;
    sd[t] = v;
    __syncthreads();
    int x = v;
    for (int off = 1; off < 256; off <<= 1) {
        int u = (t >= off) ? sd[t - off] : 0;
        __syncthreads();
        x += u;
        sd[t] = x;
        __syncthreads();
    }
    int base = blocksums[blockIdx.x];
    int e = base + x - v;
    if (i < Nn) {
        poffsets[i] = e;
        cursor[i] = e;
        if (i == Nn - 1) poffsets[Nn] = e + v;
    }
}

// ---------------- prep: scatter edges + fp16 conversions in one launch ----------------
__global__ void prep(const int* __restrict__ ei, int* cursor, int* __restrict__ csr,
                     const float* __restrict__ x, const float* __restrict__ W1,
                     const float* __restrict__ W2, _Float16* __restrict__ xh,
                     _Float16* __restrict__ w1t, _Float16* __restrict__ w2t) {
    int b = blockIdx.x, t = threadIdx.x;
    if (b < SC_BLOCKS) {
        int e = b * 256 + t;
        if (e < EE) {
            int src, dst;
            if (e < Ee) { src = ei[e]; dst = ei[Ee + e]; }
            else        { src = e - Ee; dst = e - Ee; }
            int pos = atomicAdd(&cursor[dst], 1);
            csr[pos] = src;
        }
    } else if (b < SC_BLOCKS + CONVX_BLOCKS) {
        int i = (b - SC_BLOCKS) * 256 + t;
        xh[i] = (_Float16)x[i];
    } else if (b < SC_BLOCKS + CONVX_BLOCKS + TW1_BLOCKS) {
        int bb = b - SC_BLOCKS - CONVX_BLOCKS;
        int n = (bb & 7) * 64 + (t & 63);
        int k = (bb >> 3) * 4 + (t >> 6);
        w1t[(size_t)n * INF_ + k] = (_Float16)W1[(size_t)k * F1 + n];
    } else {
        int bb = b - SC_BLOCKS - CONVX_BLOCKS - TW1_BLOCKS;
        int n = (bb & 7) * 64 + (t & 63);
        int k = (bb >> 3) * 4 + (t >> 6);
        w2t[(size_t)n * F1 + k] = (_Float16)W2[(size_t)k * F2 + n];
    }
}

// ---------------- MFMA fp16 GEMM + fused alpha dots ----------------
#define LDK 40
__global__ __launch_bounds__(256) void mfma_gemm(const _Float16* __restrict__ A,
                                                 const _Float16* __restrict__ BT,
                                                 _Float16* __restrict__ C,
                                                 const float* __restrict__ a_src,
                                                 const float* __restrict__ a_dst,
                                                 float* __restrict__ as_out,
                                                 float* __restrict__ ad_out,
                                                 int M, int K) {
    __shared__ _Float16 As[64 * LDK];
    __shared__ _Float16 Bs[128 * LDK];
    const int tid = threadIdx.x;
    const int wave = tid >> 6, lane = tid & 63;
    const int q = lane >> 4, ml = lane & 15;
    const int bm = blockIdx.x * 64, bn = blockIdx.y * 128;
    const int head = blockIdx.y;
    const int srow = tid >> 2, scol = (tid & 3) * 8;

    frag_c acc[8];
#pragma unroll
    for (int f = 0; f < 8; f++)
#pragma unroll
        for (int r = 0; r < 4; r++) acc[f][r] = 0.f;

    for (int k0 = 0; k0 < K; k0 += 32) {
        int gm = bm + srow;
        frag_ab av;
        if (gm < M) av = *(const frag_ab*)(A + (size_t)gm * K + k0 + scol);
        else {
#pragma unroll
            for (int j = 0; j < 8; j++) av[j] = (_Float16)0.f;
        }
        *(frag_ab*)&As[srow * LDK + scol] = av;
        *(frag_ab*)&Bs[srow * LDK + scol] =
            *(const frag_ab*)(BT + (size_t)(bn + srow) * K + k0 + scol);
        *(frag_ab*)&Bs[(64 + srow) * LDK + scol] =
            *(const frag_ab*)(BT + (size_t)(bn + 64 + srow) * K + k0 + scol);
        __syncthreads();
        frag_ab a = *(frag_ab*)&As[(wave * 16 + ml) * LDK + q * 8];
#pragma unroll
        for (int f = 0; f < 8; f++) {
            frag_ab b = *(frag_ab*)&Bs[(f * 16 + ml) * LDK + q * 8];
            acc[f] = __builtin_amdgcn_mfma_f32_16x16x32_f16(a, b, acc[f], 0, 0, 0);
        }
        __syncthreads();
    }
    float asum[4] = {}, dsum[4] = {};
#pragma unroll
    for (int f = 0; f < 8; f++) {
        int cl = f * 16 + ml;
        int col = bn + cl;
        float sa = a_src[head * 128 + cl];
        float da = a_dst[head * 128 + cl];
#pragma unroll
        for (int r = 0; r < 4; r++) {
            int row = bm + wave * 16 + q * 4 + r;
            if (row < M) C[(size_t)row * (NH * 128) + col] = (_Float16)acc[f][r];
            asum[r] += acc[f][r] * sa;
            dsum[r] += acc[f][r] * da;
        }
    }
#pragma unroll
    for (int r = 0; r < 4; r++) {
#pragma unroll
        for (int off = 1; off < 16; off <<= 1) {
            asum[r] += __shfl_xor(asum[r], off);
            dsum[r] += __shfl_xor(dsum[r], off);
        }
    }
    if (ml == 0) {
#pragma unroll
        for (int r = 0; r < 4; r++) {
            int row = bm + wave * 16 + q * 4 + r;
            if (row < M) {
                as_out[row * NH + head] = asum[r];
                ad_out[row * NH + head] = dsum[r];
            }
        }
    }
}

// ---------------- fused softmax + aggregation, layer 1 ----------------
// Block = 16 nodes x 1 head (head = blockIdx&3 -> XCD slice, 2.56 MB L2-resident).
// Quarter-wave = one node. Phase 1: per-head softmax, (src,w) -> LDS (CAP=64, 8.3 KB).
// ew rows padded +1 (520 B stride, bank-rotating). Phase 2: shuffle-free 8-edge-unroll.
__global__ __launch_bounds__(256) void passAB1(const int* __restrict__ poffsets,
                                               const int* __restrict__ ends,
                                               const int* __restrict__ csr,
                                               const float* __restrict__ as,
                                               const float* __restrict__ ad,
                                               const _Float16* __restrict__ hh,
                                               const float* __restrict__ b1,
                                               _Float16* __restrict__ agg) {
    __shared__ int2 ew[16][CAP + 1];
    int head = blockIdx.x & 3;
    int qw = threadIdx.x >> 4;
    int l = threadIdx.x & 15;
    int n = (blockIdx.x >> 2) * 16 + qw;
    int pstart = poffsets[n], pend = poffsets[n + 1];
    int deg = ends[n] - pstart;
    int pdeg = pend - pstart;
    float adh = ad[n * NH + head];
    float m = -1e30f;
    for (int k = l; k < deg; k += 16) {
        int src = csr[pstart + k];
        m = fmaxf(m, lrelu(as[src * NH + head] + adh));
    }
    m = fmaxf(m, __shfl_xor(m, 1));
    m = fmaxf(m, __shfl_xor(m, 2));
    m = fmaxf(m, __shfl_xor(m, 4));
    m = fmaxf(m, __shfl_xor(m, 8));
    float s = 0.f;
    for (int k = l; k < pdeg; k += 16) {
        int src = 0;
        float e = 0.f;
        if (k < deg) {
            src = csr[pstart + k];
            e = __expf(lrelu(as[src * NH + head] + adh) - m);
        }
        if (k < CAP) ew[qw][k] = make_int2(src, __float_as_int(e));
        s += e;
    }
    s += __shfl_xor(s, 1);
    s += __shfl_xor(s, 2);
    s += __shfl_xor(s, 4);
    s += __shfl_xor(s, 8);
    float inv = 1.f / (s + 1e-16f);
    __syncthreads();
    int c = head * 128 + (l << 3);
    float acc[8] = {};
    int lim = pdeg < CAP ? pdeg : CAP;
    for (int kk = 0; kk < lim; kk += 8) {
        int2 p[8];
#pragma unroll
        for (int j = 0; j < 8; j++) p[j] = ew[qw][kk + j];
#pragma unroll
        for (int j = 0; j < 8; j++) {
            float w = __int_as_float(p[j].y);
            frag_ab r = *(const frag_ab*)(hh + (size_t)p[j].x * F1 + c);
#pragma unroll
            for (int u = 0; u < 8; u++) acc[u] = fmaf((float)r[u], w, acc[u]);
        }
    }
    for (int kk = CAP; kk < pdeg; kk += 8) {   // ~never taken (P(deg>63)~6e-8)
#pragma unroll
        for (int j = 0; j < 8; j++) {
            int k = kk + j;
            int src = 0;
            float e = 0.f;
            if (k < deg) {
                src = csr[pstart + k];
                e = __expf(lrelu(as[src * NH + head] + adh) - m);
            }
            frag_ab r = *(const frag_ab*)(hh + (size_t)src * F1 + c);
#pragma unroll
            for (int u = 0; u < 8; u++) acc[u] = fmaf((float)r[u], e, acc[u]);
        }
    }
    _Float16 oh[8];
#pragma unroll
    for (int j = 0; j < 8; j++)
        oh[j] = (_Float16)fmaxf(acc[j] * inv + b1[c + j], 0.f);
    *(float4*)&agg[(size_t)n * F1 + c] = *(float4*)oh;
}

// ---------------- fused softmax + aggregation, layer 2 -> tmp ----------------
__global__ __launch_bounds__(256) void passAB2(const int* __restrict__ poffsets,
                                               const int* __restrict__ ends,
                                               const int* __restrict__ csr,
                                               const float* __restrict__ as,
                                               const float* __restrict__ ad,
                                               const _Float16* __restrict__ hh,
                                               float* __restrict__ tmp) {
    __shared__ int2 ew[16][CAP + 1];
    int head = blockIdx.x & 3;
    int qw = threadIdx.x >> 4;
    int l = threadIdx.x & 15;
    int n = (blockIdx.x >> 2) * 16 + qw;
    int pstart = poffsets[n], pend = poffsets[n + 1];
    int deg = ends[n] - pstart;
    int pdeg = pend - pstart;
    float adh = ad[n * NH + head];
    float m = -1e30f;
    for (int k = l; k < deg; k += 16) {
        int src = csr[pstart + k];
        m = fmaxf(m, lrelu(as[src * NH + head] + adh));
    }
    m = fmaxf(m, __shfl_xor(m, 1));
    m = fmaxf(m, __shfl_xor(m, 2));
    m = fmaxf(m, __shfl_xor(m, 4));
    m = fmaxf(m, __shfl_xor(m, 8));
    float s = 0.f;
    for (int k = l; k < pdeg; k += 16) {
        int src = 0;
        float e = 0.f;
        if (k < deg) {
            src = csr[pstart + k];
            e = __expf(lrelu(as[src * NH + head] + adh) - m);
        }
        if (k < CAP) ew[qw][k] = make_int2(src, __float_as_int(e));
        s += e;
    }
    s += __shfl_xor(s, 1);
    s += __shfl_xor(s, 2);
    s += __shfl_xor(s, 4);
    s += __shfl_xor(s, 8);
    float inv = 1.f / (s + 1e-16f);
    __syncthreads();
    int c = head * 128 + (l << 3);
    float acc[8] = {};
    int lim = pdeg < CAP ? pdeg : CAP;
    for (int kk = 0; kk < lim; kk += 8) {
        int2 p[8];
#pragma unroll
        for (int j = 0; j < 8; j++) p[j] = ew[qw][kk + j];
#pragma unroll
        for (int j = 0; j < 8; j++) {
            float w = __int_as_float(p[j].y);
            frag_ab r = *(const frag_ab*)(hh + (size_t)p[j].x * F2 + c);
#pragma unroll
            for (int u = 0; u < 8; u++) acc[u] = fmaf((float)r[u], w, acc[u]);
        }
    }
    for (int kk = CAP; kk < pdeg; kk += 8) {
#pragma unroll
        for (int j = 0; j < 8; j++) {
            int k = kk + j;
            int src = 0;
            float e = 0.f;
            if (k < deg) {
                src = csr[pstart + k];
                e = __expf(lrelu(as[src * NH + head] + adh) - m);
            }
            frag_ab r = *(const frag_ab*)(hh + (size_t)src * F2 + c);
#pragma unroll
            for (int u = 0; u < 8; u++) acc[u] = fmaf((float)r[u], e, acc[u]);
        }
    }
    float qq = 0.25f * inv;
    float* tp = tmp + (size_t)n * F2 + c;   // layout [n][head*128+ch]
    float4 o0 = make_float4(acc[0] * qq, acc[1] * qq, acc[2] * qq, acc[3] * qq);
    float4 o1 = make_float4(acc[4] * qq, acc[5] * qq, acc[6] * qq, acc[7] * qq);
    *(float4*)tp = o0;
    *(float4*)(tp + 4) = o1;
}

// ---------------- reduce 4 heads + bias -> d_out (tmp layout [n][head][128]) ----------------
__global__ void reduce4(const float* __restrict__ tmp, const float* __restrict__ b2,
                        float* __restrict__ out) {
    int i = blockIdx.x * 256 + threadIdx.x;
    if (i >= Nn * OUTC) return;
    int n = i >> 7, oc = i & 127;
    const float* tp = tmp + (size_t)n * 512 + oc;
    out[i] = tp[0] + tp[128] + tp[256] + tp[384] + b2[oc];
}

extern "C" void kernel_launch(void* const* d_in, const int* in_sizes, int n_in,
                              void* d_out, int out_size, void* d_ws, size_t ws_size,
                              hipStream_t stream) {
    const float* x      = (const float*)d_in[0];
    const int*   ei     = (const int*)d_in[1];
    const float* W1     = (const float*)d_in[2];
    const float* a_src1 = (const float*)d_in[3];
    const float* a_dst1 = (const float*)d_in[4];
    const float* b1     = (const float*)d_in[5];
    const float* W2     = (const float*)d_in[6];
    const float* a_src2 = (const float*)d_in[7];
    const float* a_dst2 = (const float*)d_in[8];
    const float* b2     = (const float*)d_in[9];
    float* out = (float*)d_out;

    const size_t NF = (size_t)Nn * F1;
    float* f = (float*)d_ws;
    float* tmp   = f;                    // NF floats [n][head][128]
    float* as1   = tmp + NF;
    float* ad1   = as1 + Nn * NH;
    float* as2   = ad1 + Nn * NH;
    float* ad2   = as2 + Nn * NH;
    int* csr     = (int*)(ad2 + Nn * NH);            // EEPS ints (pad-8)
    _Float16* hh   = (_Float16*)(csr + EEPS);
    _Float16* aggh = hh + NF;
    _Float16* xh   = aggh + NF;
    _Float16* w1t  = xh + (size_t)Nn * INF_;
    _Float16* w2t  = w1t + (size_t)F1 * INF_;
    int* counts    = (int*)(w2t + (size_t)F2 * F1);
    int* poffsets  = counts + Nn;
    int* cursor    = poffsets + Nn + 1;
    int* blocksums = cursor + Nn;

    // CSR build: memset counts, count edges, scan (+1 self loop, pad-8)
    (void)hipMemsetAsync(counts, 0, Nn * sizeof(int), stream);
    count_edges<<<(Ee + 255) / 256, 256, 0, stream>>>(ei, counts);
    reduce_counts<<<NB, 256, 0, stream>>>(counts, blocksums);
    scan_sums<<<1, 64, 0, stream>>>(blocksums);
    scan_final<<<NB, 256, 0, stream>>>(counts, blocksums, poffsets, cursor);

    // scatter + fp16 conversions, one launch
    prep<<<SC_BLOCKS + CONVX_BLOCKS + TW1_BLOCKS + TW2_BLOCKS, 256, 0, stream>>>(
        ei, cursor, csr, x, W1, W2, xh, w1t, w2t);

    // Layer 1
    mfma_gemm<<<dim3((Nn + 63) / 64, F1 / 128), 256, 0, stream>>>(
        xh, w1t, hh, a_src1, a_dst1, as1, ad1, Nn, INF_);
    passAB1<<<(Nn / 16) * 4, 256, 0, stream>>>(poffsets, cursor, csr, as1, ad1, hh, b1, aggh);

    // Layer 2
    mfma_gemm<<<dim3((Nn + 63) / 64, F2 / 128), 256, 0, stream>>>(
        aggh, w2t, hh, a_src2, a_dst2, as2, ad2, Nn, F1);
    passAB2<<<(Nn / 16) * 4, 256, 0, stream>>>(poffsets, cursor, csr, as2, ad2, hh, tmp);
    reduce4<<<(Nn * OUTC + 255) / 256, 256, 0, stream>>>(tmp, b2, out);
}